// Round 9
// baseline (1772.139 us; speedup 1.0000x reference)
//
#include <hip/hip_runtime.h>
#include <math.h>

#define NPROTO 8
#define KV_NCH 4
#define MSG_NCH 8

typedef __attribute__((ext_vector_type(8))) short short8;
typedef __attribute__((ext_vector_type(4))) float floatx4;

static __device__ __forceinline__ ushort f2b(float f) {
    unsigned u = __builtin_bit_cast(unsigned, f);
    unsigned r = (u + 0x7fffu + ((u >> 16) & 1u)) >> 16;
    return (ushort)r;
}

static __device__ __forceinline__ float b2f(ushort u) {
    return __builtin_bit_cast(float, ((unsigned)u) << 16);
}

typedef __attribute__((address_space(1))) void gvoid;
typedef __attribute__((address_space(3))) void lvoid;

// async global->LDS, 16B per lane. LDS dest must be lane-contiguous per wave.
static __device__ __forceinline__ void gload_lds16(const ushort* g, ushort* l) {
    __builtin_amdgcn_global_load_lds((gvoid*)(void*)g, (lvoid*)l, 16, 0, 0);
}

// ---------------- prototype projection / argmax-class kernel ----------------
__global__ __launch_bounds__(256) void lft_class_kernel(
    const float* __restrict__ f0wo, const float* __restrict__ f1wo,
    const int* __restrict__ mask0, const int* __restrict__ mask1,
    const float* __restrict__ proto,
    float* out, int* cls0, int* cls1)
{
    __shared__ float pr[2048];
    int t = threadIdx.x;
    *(float4*)&pr[t * 4]        = *(const float4*)&proto[t * 4];
    *(float4*)&pr[1024 + t * 4] = *(const float4*)&proto[1024 + t * 4];
    __syncthreads();
    int wave = t >> 6, lane = t & 63;
    long token = (long)blockIdx.x * 4 + wave;
    const float* fsrc; const int* msrc; float* fpout; float* clsout; int* clsarr; long tok;
    if (token < 38400) {
        tok = token; fsrc = f0wo; msrc = mask0;
        fpout = out + 19737600L; clsout = out + 19660800L; clsarr = cls0;
    } else {
        tok = token - 38400; fsrc = f1wo; msrc = mask1;
        fpout = out + 20044800L; clsout = out + 19699200L; clsarr = cls1;
    }
    float4 f = *(const float4*)&fsrc[tok * 256 + lane * 4];
    float s[NPROTO];
#pragma unroll
    for (int p = 0; p < NPROTO; p++) {
        float4 pv = *(const float4*)&pr[p * 256 + lane * 4];
        s[p] = f.x * pv.x + f.y * pv.y + f.z * pv.z + f.w * pv.w;
    }
    float k0_ = (lane & 1) ? s[4] : s[0], d0 = (lane & 1) ? s[0] : s[4];
    float k1_ = (lane & 1) ? s[5] : s[1], d1 = (lane & 1) ? s[1] : s[5];
    float k2_ = (lane & 1) ? s[6] : s[2], d2 = (lane & 1) ? s[2] : s[6];
    float k3_ = (lane & 1) ? s[7] : s[3], d3 = (lane & 1) ? s[3] : s[7];
    float w0 = k0_ + __shfl_xor(d0, 1, 64);
    float w1 = k1_ + __shfl_xor(d1, 1, 64);
    float w2 = k2_ + __shfl_xor(d2, 1, 64);
    float w3 = k3_ + __shfl_xor(d3, 1, 64);
    float u0k = (lane & 2) ? w2 : w0, u0d = (lane & 2) ? w0 : w2;
    float u1k = (lane & 2) ? w3 : w1, u1d = (lane & 2) ? w1 : w3;
    float x0 = u0k + __shfl_xor(u0d, 2, 64);
    float x1 = u1k + __shfl_xor(u1d, 2, 64);
    float yk = (lane & 4) ? x1 : x0, yd = (lane & 4) ? x0 : x1;
    float sc = yk + __shfl_xor(yd, 4, 64);
    sc += __shfl_xor(sc, 8, 64);
    sc += __shfl_xor(sc, 16, 64);
    sc += __shfl_xor(sc, 32, 64);
    int p = ((lane & 1) << 2) | (lane & 2) | ((lane >> 2) & 1);
    if (lane < 8) fpout[tok * 8 + p] = sc;
    float bv = sc; int bi = p;
#pragma unroll
    for (int o = 1; o < 8; o <<= 1) {
        float ov = __shfl_xor(bv, o, 64);
        int oi = __shfl_xor(bi, o, 64);
        if (ov > bv || (ov == bv && oi < bi)) { bv = ov; bi = oi; }
    }
    if (lane == 0) {
        clsout[tok] = (float)bi;
        clsarr[tok] = msrc[tok] ? bi : -1;
    }
}

// ---------------- counting sort of tokens by (batch,class) -------------------
__global__ __launch_bounds__(256) void lft_sort_kernel(
    const int* __restrict__ cls0, const int* __restrict__ cls1,
    int* tl0, int* tl1, int* meta)
{
    int g = blockIdx.x; int L = g >> 3, b = g & 7;
    const int* cls = (L ? cls1 : cls0) + b * 4800;
    int* tl = (L ? tl1 : tl0) + b * 4800;
    int* mt = meta + (L * 8 + b) * 16;
    __shared__ int cnt[8], base[8], pos[8];
    int t = threadIdx.x;
    if (t < 8) cnt[t] = 0;
    __syncthreads();
    for (int tok = t; tok < 4800; tok += 256) {
        int c = cls[tok];
        if (c >= 0) atomicAdd(&cnt[c], 1);
    }
    __syncthreads();
    if (t == 0) {
        int s = 0;
        for (int c = 0; c < 8; c++) { base[c] = s; pos[c] = s; s += cnt[c]; }
    }
    __syncthreads();
    if (t < 8) { mt[t * 2] = base[t]; mt[t * 2 + 1] = cnt[t]; }
    for (int tok = t; tok < 4800; tok += 256) {
        int c = cls[tok];
        if (c >= 0) { int p = atomicAdd(&pos[c], 1); tl[p] = tok; }
    }
}

// ---------------- weight convert + transpose: Wt[n*K+k] = bf16(W[k*N+n]) ----
__global__ __launch_bounds__(256) void lft_wconv_kernel(
    const float* W0, const float* W1p, const float* W2p, const float* W3p,
    int K, int N, int nTypes, ushort* dst)
{
    int z = blockIdx.z;
    int li = z / nTypes, mi = z % nTypes;
    const float* srcs[4] = {W0, W1p, W2p, W3p};
    const float* src = srcs[mi] + (size_t)li * K * N;
    ushort* outp = dst + (size_t)z * K * N;
    __shared__ float tile[32][33];
    int k0 = blockIdx.x * 32, n0 = blockIdx.y * 32;
    int t = threadIdx.x;
    int r = t >> 3, c4 = (t & 7) << 2;
    float4 v = *(const float4*)&src[(size_t)(k0 + r) * N + n0 + c4];
    tile[r][c4] = v.x; tile[r][c4 + 1] = v.y; tile[r][c4 + 2] = v.z; tile[r][c4 + 3] = v.w;
    __syncthreads();
    ushort4 o;
    o.x = f2b(tile[c4 + 0][r]);
    o.y = f2b(tile[c4 + 1][r]);
    o.z = f2b(tile[c4 + 2][r]);
    o.w = f2b(tile[c4 + 3][r]);
    *(ushort4*)&outp[(size_t)(n0 + r) * K + k0 + c4] = o;
}

// ---------------- bf16 cast of feat0/feat1 (shadows only) ----------------
__global__ __launch_bounds__(256) void lft_cast_kernel(
    const float* __restrict__ f0, const float* __restrict__ f1,
    ushort* fab, ushort* fbb)
{
    long idx = ((long)blockIdx.x * 256 + threadIdx.x) * 4;
    const float* src; ushort* db; long o;
    if (idx < 9830400L) { src = f0; db = fab; o = idx; }
    else                { src = f1; db = fbb; o = idx - 9830400L; }
    float4 v = *(const float4*)&src[o];
    ushort4 u; u.x = f2b(v.x); u.y = f2b(v.y); u.z = f2b(v.z); u.w = f2b(v.w);
    *(ushort4*)&db[o] = u;
}

// ---------------- bf16 MFMA GEMM, BK=64 2-phase: C = act([A0|A1] @ Wt^T) ----
// 128x128 tile, BK=64 (half the barriers/K vs BK=32; 32 MFMA per step),
// double-buffered 64KB LDS, global_load_lds dwordx4, counted vmcnt(8).
// Swizzle (rule #21): LDS[row][u] holds global unit u^(row&7); read applies
// same XOR -> 2-way banks. TRANSPOSED-OPERAND vectorized epilogue.
// Optional split output (Cb2/N2/colSplit): block-uniform dest select by n0.
__global__ __launch_bounds__(256) void lft_mfma_gemm(
    const ushort* __restrict__ A0, const ushort* __restrict__ A1, int kSplit,
    const ushort* __restrict__ Wt,
    float* Cf, ushort* Cb, int N, int K, int act, int actSplit,
    ushort* Cb2, int N2, int colSplit)
{
    __shared__ ushort As[2][128 * 64];
    __shared__ ushort Bs[2][128 * 64];
    int t = threadIdx.x;
    // ---- XCD swizzle: logical tile id = chunked remap of hardware id ----
    int nbx = gridDim.x;
    int nwg = nbx * gridDim.y;
    int orig = blockIdx.y * nbx + blockIdx.x;
    int q8 = nwg >> 3;
    int swz = (nwg & 7) ? orig : ((orig & 7) * q8 + (orig >> 3));
    int bx = swz % nbx, by = swz / nbx;
    int m0 = by << 7;
    int n0 = bx << 7;
    int wave = t >> 6, lane = t & 63;
    int wm = wave >> 1, wn = wave & 1;
    int l16 = lane & 15, quad = lane >> 4;
    int rw = t >> 3;                 // 0..31: row within a 32-row staging slab
    int cw = (t & 7) << 3;           // linear LDS col offset (ushorts), 8x16B units
    int fso = (((t & 7) ^ ((t >> 3) & 7)) << 3);  // swizzled SOURCE col offset
    floatx4 acc[4][4] = {};

    auto stage = [&](int buf, int k0) {
        const ushort* Asrc; int kcol, ldA;
        if (k0 < kSplit) { Asrc = A0; kcol = k0;          ldA = kSplit; }
        else             { Asrc = A1; kcol = k0 - kSplit; ldA = K - kSplit; }
#pragma unroll
        for (int i = 0; i < 4; i++) {
            gload_lds16(&Asrc[(size_t)(m0 + i * 32 + rw) * ldA + kcol + fso],
                        &As[buf][(i * 32 + rw) * 64 + cw]);
            gload_lds16(&Wt[(size_t)(n0 + i * 32 + rw) * K + k0 + fso],
                        &Bs[buf][(i * 32 + rw) * 64 + cw]);
        }
    };

    stage(0, 0);
    int cur = 0;
    for (int k0 = 0; k0 < K; k0 += 64) {
        if (k0 + 64 < K) {
            stage(cur ^ 1, k0 + 64);
            asm volatile("s_waitcnt vmcnt(8)" ::: "memory");
        } else {
            asm volatile("s_waitcnt vmcnt(0)" ::: "memory");
        }
        __builtin_amdgcn_s_barrier();
#pragma unroll
        for (int ks = 0; ks < 2; ks++) {
            short8 af[4], bfr[4];
            int ua = (((ks * 4 + quad) ^ (l16 & 7)) << 3);  // swizzled READ col
#pragma unroll
            for (int i = 0; i < 4; i++) {
                af[i]  = *(const short8*)&As[cur][(wm * 64 + i * 16 + l16) * 64 + ua];
                bfr[i] = *(const short8*)&Bs[cur][(wn * 64 + i * 16 + l16) * 64 + ua];
            }
            // operand order (B, A): output fragment transposed -> lane l16 = row,
            // quad*4+rr = 4 consecutive cols (enables ushort4/float4 stores).
#pragma unroll
            for (int i = 0; i < 4; i++)
#pragma unroll
                for (int j = 0; j < 4; j++)
                    acc[i][j] = __builtin_amdgcn_mfma_f32_16x16x32_bf16(bfr[j], af[i], acc[i][j], 0, 0, 0);
        }
        asm volatile("" ::: "memory");
        __builtin_amdgcn_s_barrier();
        cur ^= 1;
    }
    int effAct = (n0 >= actSplit) ? 0 : act;
    float* Cfp = Cf;
    ushort* Cbp = Cb;
    int ldC = N, cb0 = n0;
    if (Cb2 && n0 >= colSplit) { Cbp = Cb2; Cfp = nullptr; ldC = N2; cb0 = n0 - colSplit; }
#pragma unroll
    for (int i = 0; i < 4; i++) {
        long rowb = m0 + wm * 64 + i * 16 + l16;
#pragma unroll
        for (int j = 0; j < 4; j++) {
            int colb = cb0 + wn * 64 + j * 16 + quad * 4;
            float v0 = acc[i][j][0], v1 = acc[i][j][1], v2 = acc[i][j][2], v3 = acc[i][j][3];
            if (effAct == 1) {
                v0 = v0 > 0.f ? v0 + 1.f : __expf(v0);
                v1 = v1 > 0.f ? v1 + 1.f : __expf(v1);
                v2 = v2 > 0.f ? v2 + 1.f : __expf(v2);
                v3 = v3 > 0.f ? v3 + 1.f : __expf(v3);
            } else if (effAct == 2) {
                v0 = fmaxf(v0, 0.f); v1 = fmaxf(v1, 0.f);
                v2 = fmaxf(v2, 0.f); v3 = fmaxf(v3, 0.f);
            }
            if (Cfp) {
                float4 f4; f4.x = v0; f4.y = v1; f4.z = v2; f4.w = v3;
                *(float4*)&Cfp[rowb * ldC + colb] = f4;
            }
            if (Cbp) {
                ushort4 u4;
                u4.x = f2b(v0); u4.y = f2b(v1); u4.z = f2b(v2); u4.w = f2b(v3);
                *(ushort4*)&Cbp[rowb * ldC + colb] = u4;
            }
        }
    }
}

// ---------------- per-class KV / Ksum reduction (SRC-side token lists) --------
// kvab: fused bf16 [38400][512], cols 0..255 = phi_k, 256..511 = v
__global__ __launch_bounds__(256) void lft_kv_kernel(
    const ushort* __restrict__ kvab,
    const int* __restrict__ tlist, const int* __restrict__ meta,
    float* kv, float* ksum)
{
    int chunk = blockIdx.x, c = blockIdx.y;
    int b = blockIdx.z >> 3, h = blockIdx.z & 7;
    int off = meta[(b * 8 + c) * 2], n = meta[(b * 8 + c) * 2 + 1];
    int per = (n + KV_NCH - 1) / KV_NCH;
    int s0 = chunk * per;
    int s1 = min(s0 + per, n);
    if (s0 >= s1) return;
    const int* tl = tlist + b * 4800 + off;
    int t = threadIdx.x;
    __shared__ float kb[8][32];
    __shared__ float vb[8][32];
    int od = t >> 3, oe = (t & 7) << 2;
    int lt = t >> 5, ld = t & 31;
    float a0 = 0.f, a1 = 0.f, a2 = 0.f, a3 = 0.f, ak = 0.f;
    for (int s = s0; s < s1; s += 8) {
        float kval = 0.f, vval = 0.f;
        if (s + lt < s1) {
            int tok = tl[s + lt];
            long bse = ((long)b * 4800 + tok) * 512 + h * 32 + ld;
            kval = b2f(kvab[bse]);
            vval = b2f(kvab[bse + 256]);
        }
        __syncthreads();
        kb[lt][ld] = kval;
        vb[lt][ld] = vval;
        __syncthreads();
#pragma unroll
        for (int j = 0; j < 8; j++) {
            float kd = kb[j][od];
            float4 vv = *(const float4*)&vb[j][oe];
            a0 += kd * vv.x; a1 += kd * vv.y; a2 += kd * vv.z; a3 += kd * vv.w;
            ak += kd;
        }
    }
    float* dst = kv + (((long)(b * NPROTO + c) * 8 + h) << 10) + od * 32 + oe;
    atomicAdd(dst + 0, a0);
    atomicAdd(dst + 1, a1);
    atomicAdd(dst + 2, a2);
    atomicAdd(dst + 3, a3);
    if ((t & 7) == 0)
        atomicAdd(ksum + (((long)(b * NPROTO + c) * 8 + h) << 5) + od, ak);
}

// ---------------- kv fp32 [d][e] + ksum → bf16 B-layout [e'][d], e'<48 -------
__global__ __launch_bounds__(256) void lft_kvconv_kernel(
    const float* __restrict__ kvb, const float* __restrict__ ksb,
    ushort* __restrict__ kvt)
{
    int bc = blockIdx.x;          // b*8+c
    int t = threadIdx.x;
    int h = t >> 5, d = t & 31;
    const float* kvsrc = kvb + ((long)bc * 8 + h) * 1024;
    const float* kssrc = ksb + ((long)bc * 8 + h) * 32;
    ushort* dst = kvt + ((long)bc * 8 + h) * 1536;
#pragma unroll
    for (int e = 0; e < 32; e++) dst[e * 32 + d] = f2b(kvsrc[d * 32 + e]);
    dst[32 * 32 + d] = f2b(kssrc[d]);
#pragma unroll
    for (int e = 33; e < 48; e++) dst[e * 32 + d] = 0;
}

// ---------------- msg via MFMA over X-SIDE class-sorted lists ----------------
__global__ __launch_bounds__(256) void lft_msg_kernel(
    const ushort* __restrict__ pq, const ushort* __restrict__ kvt,
    const int* __restrict__ tlist, const int* __restrict__ meta,
    ushort* __restrict__ msg)
{
    int chunk = blockIdx.x, c = blockIdx.y, b = blockIdx.z;
    int off = meta[(b * 8 + c) * 2], n = meta[(b * 8 + c) * 2 + 1];
    int per = (n + MSG_NCH - 1) / MSG_NCH;
    int s0 = chunk * per, s1 = min(s0 + per, n);
    if (s0 >= s1) return;
    const int* tl = tlist + b * 4800 + off;
    int t = threadIdx.x;
    int wave = t >> 6, lane = t & 63;
    int l16 = lane & 15, quad = lane >> 4;
    int bc = b * 8 + c;
    short8 bfr[2][3];
#pragma unroll
    for (int hh = 0; hh < 2; hh++) {
        int h = wave * 2 + hh;
        const ushort* kb = kvt + ((long)bc * 8 + h) * 1536;
#pragma unroll
        for (int nt = 0; nt < 3; nt++)
            bfr[hh][nt] = *(const short8*)&kb[(nt * 16 + l16) * 32 + quad * 8];
    }
    for (int s = s0; s < s1; s += 16) {
        int ia = min(s + l16, s1 - 1);
        int tokA = tl[ia];
        long rowA = (long)b * 4800 + tokA;
#pragma unroll
        for (int hh = 0; hh < 2; hh++) {
            int h = wave * 2 + hh;
            short8 a = *(const short8*)&pq[rowA * 256 + h * 32 + quad * 8];
            floatx4 n0 = {}, n1 = {}, dd = {};
            n0 = __builtin_amdgcn_mfma_f32_16x16x32_bf16(a, bfr[hh][0], n0, 0, 0, 0);
            n1 = __builtin_amdgcn_mfma_f32_16x16x32_bf16(a, bfr[hh][1], n1, 0, 0, 0);
            dd = __builtin_amdgcn_mfma_f32_16x16x32_bf16(a, bfr[hh][2], dd, 0, 0, 0);
#pragma unroll
            for (int r = 0; r < 4; r++) {
                int rowi = s + quad * 4 + r;
                float den = __shfl(dd[r], lane & 48, 64);
                float inv = 1.f / (den + 1e-6f);
                int tokr = __shfl(tokA, quad * 4 + r, 64);
                if (rowi < s1) {
                    long base = ((long)b * 4800 + tokr) * 256 + h * 32;
                    msg[base + l16]      = f2b(n0[r] * inv);
                    msg[base + 16 + l16] = f2b(n1[r] * inv);
                }
            }
        }
    }
}

// ---------------- row LayerNorm (256) over BF16 input, optional resid+mask ---
__global__ __launch_bounds__(256) void lft_lnb_kernel(
    const ushort* __restrict__ in, float* outF, ushort* outB,
    const float* __restrict__ g, const float* __restrict__ bb,
    const float* resid, const int* __restrict__ cls)
{
    int wave = threadIdx.x >> 6, lane = threadIdx.x & 63;
    long row = (long)blockIdx.x * 4 + wave;
    ushort4 xb = *(const ushort4*)&in[row * 256 + lane * 4];
    float xx = b2f(xb.x), xy = b2f(xb.y), xz = b2f(xb.z), xw = b2f(xb.w);
    float s = xx + xy + xz + xw;
#pragma unroll
    for (int o = 32; o >= 1; o >>= 1) s += __shfl_xor(s, o, 64);
    float mean = s * (1.0f / 256.0f);
    float dx = xx - mean, dy = xy - mean, dz = xz - mean, dw = xw - mean;
    float vs = dx * dx + dy * dy + dz * dz + dw * dw;
#pragma unroll
    for (int o = 32; o >= 1; o >>= 1) vs += __shfl_xor(vs, o, 64);
    float r = rsqrtf(vs * (1.0f / 256.0f) + 1e-5f);
    float4 gv = *(const float4*)&g[lane * 4];
    float4 bv = *(const float4*)&bb[lane * 4];
    float4 y;
    y.x = dx * r * gv.x + bv.x;
    y.y = dy * r * gv.y + bv.y;
    y.z = dz * r * gv.z + bv.z;
    y.w = dw * r * gv.w + bv.w;
    if (resid) {
        float4 xr = *(const float4*)&resid[row * 256 + lane * 4];
        if (cls[row] >= 0) { y.x += xr.x; y.y += xr.y; y.z += xr.z; y.w += xr.w; }
        else y = xr;
    }
    if (outF) *(float4*)&outF[row * 256 + lane * 4] = y;
    if (outB) {
        ushort4 u; u.x = f2b(y.x); u.y = f2b(y.y); u.z = f2b(y.z); u.w = f2b(y.w);
        *(ushort4*)&outB[row * 256 + lane * 4] = u;
    }
}

extern "C" void kernel_launch(void* const* d_in, const int* in_sizes, int n_in,
                              void* d_out, int out_size, void* d_ws, size_t ws_size,
                              hipStream_t stream)
{
    (void)in_sizes; (void)n_in; (void)out_size; (void)ws_size;
    const float* feat0 = (const float*)d_in[0];
    const float* feat1 = (const float*)d_in[1];
    const int*   mask0 = (const int*)d_in[2];
    const int*   mask1 = (const int*)d_in[3];
    const float* f0wo  = (const float*)d_in[4];
    const float* f1wo  = (const float*)d_in[5];
    const float* proto = (const float*)d_in[6];
    const float* Wq = (const float*)d_in[7];
    const float* Wk = (const float*)d_in[8];
    const float* Wv = (const float*)d_in[9];
    const float* Wm = (const float*)d_in[10];
    const float* W1 = (const float*)d_in[11];
    const float* W2 = (const float*)d_in[12];
    const float* g1 = (const float*)d_in[13];
    const float* b1 = (const float*)d_in[14];
    const float* g2 = (const float*)d_in[15];
    const float* b2 = (const float*)d_in[16];
    float* out = (float*)d_out;
    float* ws = (float*)d_ws;

    // ---- workspace layout ----
    const long FSZ = 9830400L;           // 8*4800*256
    float* fa   = ws;                    // fp32 master feat0
    float* fb   = ws + FSZ;              // fp32 master feat1
    float* kbuf = ws + 2 * FSZ;          // bf16 GEMM outs (Wm, W2) -- bounce buffer
    float* vbuf = ws + 3 * FSZ;          // bf16 [38400][512]: kv fused out, later hid
    ushort* ub  = (ushort*)(ws + 4 * FSZ);
    ushort* fa_bf  = ub;                 // bf16 shadow of fa
    ushort* fb_bf  = ub + FSZ;           // bf16 shadow of fb
    ushort* msg_bf = ub + 2 * FSZ;       // msg bf16; later LN1 bf16 out
    ushort* qb_bf  = ub + 3 * FSZ;       // phi_q bf16
    ushort* wb     = ub + 4 * FSZ;       // bf16 transposed weights
    ushort* wb1    = wb + 16 * 65536;    // W1^T per layer [512][512]
    ushort* wb2    = wb1 + 4 * 262144;   // W2^T per layer [256][512]
    ushort* kvt    = wb2 + 4 * 131072;   // [64][8][48][32] bf16
    float* kvb = (float*)(kvt + 786432); // [B,NP,H,D,D] = 524288 f
    float* ksb = kvb + 524288;           // [B,NP,H,D]   = 16384 f
    int* cls0 = (int*)(ksb + 16384);
    int* cls1 = cls0 + 38400;
    int* tl0  = cls1 + 38400;            // class-sorted token lists
    int* tl1  = tl0 + 38400;
    int* meta = tl1 + 38400;             // [2][8][8][2] (off,cnt)
    ushort* kvab   = (ushort*)vbuf;      // [38400,512] bf16: [phi_k | v]
    ushort* hid_bf = (ushort*)vbuf;      // [38400,512] bf16 (after kv consumed)
    ushort* mb_bf  = (ushort*)kbuf;      // [38400,256] bf16 GEMM-out bounce

    // one-time per launch
    lft_wconv_kernel<<<dim3(8, 8, 16), 256, 0, stream>>>(Wq, Wk, Wv, Wm, 256, 256, 4, wb);
    lft_wconv_kernel<<<dim3(16, 16, 4), 256, 0, stream>>>(W1, W1, W1, W1, 512, 512, 1, wb1);
    lft_wconv_kernel<<<dim3(16, 8, 4), 256, 0, stream>>>(W2, W2, W2, W2, 512, 256, 1, wb2);
    lft_cast_kernel<<<19200, 256, 0, stream>>>(feat0, feat1, fa_bf, fb_bf);
    hipMemcpyAsync(out + 20352000L, proto, 2048 * 4, hipMemcpyDeviceToDevice, stream);
    lft_class_kernel<<<19200, 256, 0, stream>>>(f0wo, f1wo, mask0, mask1, proto,
                                                out, cls0, cls1);
    lft_sort_kernel<<<16, 256, 0, stream>>>(cls0, cls1, tl0, tl1, meta);

    for (int li = 0; li < 4; li++) {
        const ushort* wq = wb + (size_t)(li * 4 + 0) * 65536;  // wq|wk|wv contig: [768][256]
        const ushort* wk = wb + (size_t)(li * 4 + 1) * 65536;  // wk|wv contiguous: [512][256]
        const ushort* wm = wb + (size_t)(li * 4 + 3) * 65536;
        const ushort* w1 = wb1 + (size_t)li * 262144;
        const ushort* w2 = wb2 + (size_t)li * 131072;
        const float* g1p = g1 + li * 256; const float* b1p = b1 + li * 256;
        const float* g2p = g2 + li * 256; const float* b2p = b2 + li * 256;

        auto call = [&](ushort* x_bf, ushort* s_bf, const int* clsx,
                        const int* tlx, const int* mtx,
                        const int* tls, const int* mts,
                        const float* residp, float* outFp) {
            dim3 blk(256);
            dim3 gA(2, 300), gB(4, 300), gQ(6, 300);
            if (x_bf == s_bf) {
                // self-self: fused [q|phi_k|v] = x@[Wq|Wk|Wv], N=768, split out:
                // cols<256 -> qb_bf (N=256), cols>=256 -> kvab (N=512)
                lft_mfma_gemm<<<gQ, blk, 0, stream>>>(x_bf, x_bf, 256, wq,
                    nullptr, qb_bf, 256, 256, 1, 512, kvab, 512, 256);
            } else {
                lft_mfma_gemm<<<gA, blk, 0, stream>>>(x_bf, x_bf, 256, wq,
                    nullptr, qb_bf, 256, 256, 1, 256, nullptr, 0, 0);
                lft_mfma_gemm<<<gB, blk, 0, stream>>>(s_bf, s_bf, 256, wk,
                    nullptr, kvab, 512, 256, 1, 256, nullptr, 0, 0);
            }
            hipMemsetAsync(kvb, 0, (524288 + 16384) * 4, stream);
            lft_kv_kernel<<<dim3(KV_NCH, 8, 64), blk, 0, stream>>>(kvab, tls, mts, kvb, ksb);
            lft_kvconv_kernel<<<64, blk, 0, stream>>>(kvb, ksb, kvt);
            lft_msg_kernel<<<dim3(MSG_NCH, 8, 8), blk, 0, stream>>>(qb_bf, kvt, tlx, mtx, msg_bf);
            // msg = LN(msg @ Wm)*g1+b1  -- GEMM out bf16, LN reads bf16
            lft_mfma_gemm<<<gA, blk, 0, stream>>>(msg_bf, msg_bf, 256, wm,
                nullptr, mb_bf, 256, 256, 0, 256, nullptr, 0, 0);
            lft_lnb_kernel<<<9600, blk, 0, stream>>>(mb_bf, nullptr, msg_bf, g1p, b1p, nullptr, nullptr);
            // hid = relu([x|msg]@W1) (bf16) ; m = hid@W2 (bf16) ; out = valid ? resid+LN(m) : resid
            lft_mfma_gemm<<<gB, blk, 0, stream>>>(x_bf, msg_bf, 256, w1,
                nullptr, hid_bf, 512, 512, 2, 512, nullptr, 0, 0);
            lft_mfma_gemm<<<gA, blk, 0, stream>>>(hid_bf, hid_bf, 512, w2,
                nullptr, mb_bf, 256, 512, 0, 256, nullptr, 0, 0);
            lft_lnb_kernel<<<9600, blk, 0, stream>>>(mb_bf, outFp, x_bf, g2p, b2p, residp, clsx);
        };

        const float* ra = (li == 0) ? feat0 : fa;
        const float* rb = (li == 0) ? feat1 : fb;
        float* oa = (li == 3) ? out : fa;
        float* ob = (li == 3) ? (out + FSZ) : fb;

        if ((li & 1) == 0) {           // self-self
            call(fa_bf, fa_bf, cls0, tl0, meta,       tl0, meta,       ra, oa);
            call(fb_bf, fb_bf, cls1, tl1, meta + 128, tl1, meta + 128, rb, ob);
        } else {                       // cross-self: x=feat0 iterates tl0, gathers tl1
            call(fa_bf, fb_bf, cls0, tl0, meta,       tl1, meta + 128, ra, oa);
            call(fb_bf, fa_bf, cls1, tl1, meta + 128, tl0, meta,      rb, ob);
        }
    }
}

// Round 10
// 1663.317 us; speedup vs baseline: 1.0654x; 1.0654x over previous
//
#include <hip/hip_runtime.h>
#include <math.h>

#define NPROTO 8
#define KV_NCH 4
#define MSG_NCH 8

typedef __attribute__((ext_vector_type(8))) short short8;
typedef __attribute__((ext_vector_type(4))) float floatx4;

static __device__ __forceinline__ ushort f2b(float f) {
    unsigned u = __builtin_bit_cast(unsigned, f);
    unsigned r = (u + 0x7fffu + ((u >> 16) & 1u)) >> 16;
    return (ushort)r;
}

static __device__ __forceinline__ float b2f(ushort u) {
    return __builtin_bit_cast(float, ((unsigned)u) << 16);
}

typedef __attribute__((address_space(1))) void gvoid;
typedef __attribute__((address_space(3))) void lvoid;

// async global->LDS, 16B per lane. LDS dest must be lane-contiguous per wave.
static __device__ __forceinline__ void gload_lds16(const ushort* g, ushort* l) {
    __builtin_amdgcn_global_load_lds((gvoid*)(void*)g, (lvoid*)l, 16, 0, 0);
}

// ---------------- prototype projection / argmax-class kernel ----------------
__global__ __launch_bounds__(256) void lft_class_kernel(
    const float* __restrict__ f0wo, const float* __restrict__ f1wo,
    const int* __restrict__ mask0, const int* __restrict__ mask1,
    const float* __restrict__ proto,
    float* out, int* cls0, int* cls1)
{
    __shared__ float pr[2048];
    int t = threadIdx.x;
    *(float4*)&pr[t * 4]        = *(const float4*)&proto[t * 4];
    *(float4*)&pr[1024 + t * 4] = *(const float4*)&proto[1024 + t * 4];
    __syncthreads();
    int wave = t >> 6, lane = t & 63;
    long token = (long)blockIdx.x * 4 + wave;
    const float* fsrc; const int* msrc; float* fpout; float* clsout; int* clsarr; long tok;
    if (token < 38400) {
        tok = token; fsrc = f0wo; msrc = mask0;
        fpout = out + 19737600L; clsout = out + 19660800L; clsarr = cls0;
    } else {
        tok = token - 38400; fsrc = f1wo; msrc = mask1;
        fpout = out + 20044800L; clsout = out + 19699200L; clsarr = cls1;
    }
    float4 f = *(const float4*)&fsrc[tok * 256 + lane * 4];
    float s[NPROTO];
#pragma unroll
    for (int p = 0; p < NPROTO; p++) {
        float4 pv = *(const float4*)&pr[p * 256 + lane * 4];
        s[p] = f.x * pv.x + f.y * pv.y + f.z * pv.z + f.w * pv.w;
    }
    float k0_ = (lane & 1) ? s[4] : s[0], d0 = (lane & 1) ? s[0] : s[4];
    float k1_ = (lane & 1) ? s[5] : s[1], d1 = (lane & 1) ? s[1] : s[5];
    float k2_ = (lane & 1) ? s[6] : s[2], d2 = (lane & 1) ? s[2] : s[6];
    float k3_ = (lane & 1) ? s[7] : s[3], d3 = (lane & 1) ? s[3] : s[7];
    float w0 = k0_ + __shfl_xor(d0, 1, 64);
    float w1 = k1_ + __shfl_xor(d1, 1, 64);
    float w2 = k2_ + __shfl_xor(d2, 1, 64);
    float w3 = k3_ + __shfl_xor(d3, 1, 64);
    float u0k = (lane & 2) ? w2 : w0, u0d = (lane & 2) ? w0 : w2;
    float u1k = (lane & 2) ? w3 : w1, u1d = (lane & 2) ? w1 : w3;
    float x0 = u0k + __shfl_xor(u0d, 2, 64);
    float x1 = u1k + __shfl_xor(u1d, 2, 64);
    float yk = (lane & 4) ? x1 : x0, yd = (lane & 4) ? x0 : x1;
    float sc = yk + __shfl_xor(yd, 4, 64);
    sc += __shfl_xor(sc, 8, 64);
    sc += __shfl_xor(sc, 16, 64);
    sc += __shfl_xor(sc, 32, 64);
    int p = ((lane & 1) << 2) | (lane & 2) | ((lane >> 2) & 1);
    if (lane < 8) fpout[tok * 8 + p] = sc;
    float bv = sc; int bi = p;
#pragma unroll
    for (int o = 1; o < 8; o <<= 1) {
        float ov = __shfl_xor(bv, o, 64);
        int oi = __shfl_xor(bi, o, 64);
        if (ov > bv || (ov == bv && oi < bi)) { bv = ov; bi = oi; }
    }
    if (lane == 0) {
        clsout[tok] = (float)bi;
        clsarr[tok] = msrc[tok] ? bi : -1;
    }
}

// ---------------- counting sort of tokens by (batch,class) -------------------
__global__ __launch_bounds__(256) void lft_sort_kernel(
    const int* __restrict__ cls0, const int* __restrict__ cls1,
    int* tl0, int* tl1, int* meta)
{
    int g = blockIdx.x; int L = g >> 3, b = g & 7;
    const int* cls = (L ? cls1 : cls0) + b * 4800;
    int* tl = (L ? tl1 : tl0) + b * 4800;
    int* mt = meta + (L * 8 + b) * 16;
    __shared__ int cnt[8], base[8], pos[8];
    int t = threadIdx.x;
    if (t < 8) cnt[t] = 0;
    __syncthreads();
    for (int tok = t; tok < 4800; tok += 256) {
        int c = cls[tok];
        if (c >= 0) atomicAdd(&cnt[c], 1);
    }
    __syncthreads();
    if (t == 0) {
        int s = 0;
        for (int c = 0; c < 8; c++) { base[c] = s; pos[c] = s; s += cnt[c]; }
    }
    __syncthreads();
    if (t < 8) { mt[t * 2] = base[t]; mt[t * 2 + 1] = cnt[t]; }
    for (int tok = t; tok < 4800; tok += 256) {
        int c = cls[tok];
        if (c >= 0) { int p = atomicAdd(&pos[c], 1); tl[p] = tok; }
    }
}

// ---------------- weight convert + transpose: Wt[n*K+k] = bf16(W[k*N+n]) ----
__global__ __launch_bounds__(256) void lft_wconv_kernel(
    const float* W0, const float* W1p, const float* W2p, const float* W3p,
    int K, int N, int nTypes, ushort* dst)
{
    int z = blockIdx.z;
    int li = z / nTypes, mi = z % nTypes;
    const float* srcs[4] = {W0, W1p, W2p, W3p};
    const float* src = srcs[mi] + (size_t)li * K * N;
    ushort* outp = dst + (size_t)z * K * N;
    __shared__ float tile[32][33];
    int k0 = blockIdx.x * 32, n0 = blockIdx.y * 32;
    int t = threadIdx.x;
    int r = t >> 3, c4 = (t & 7) << 2;
    float4 v = *(const float4*)&src[(size_t)(k0 + r) * N + n0 + c4];
    tile[r][c4] = v.x; tile[r][c4 + 1] = v.y; tile[r][c4 + 2] = v.z; tile[r][c4 + 3] = v.w;
    __syncthreads();
    ushort4 o;
    o.x = f2b(tile[c4 + 0][r]);
    o.y = f2b(tile[c4 + 1][r]);
    o.z = f2b(tile[c4 + 2][r]);
    o.w = f2b(tile[c4 + 3][r]);
    *(ushort4*)&outp[(size_t)(n0 + r) * K + k0 + c4] = o;
}

// ---------------- bf16 cast of feat0/feat1 (shadows only) ----------------
__global__ __launch_bounds__(256) void lft_cast_kernel(
    const float* __restrict__ f0, const float* __restrict__ f1,
    ushort* fab, ushort* fbb)
{
    long idx = ((long)blockIdx.x * 256 + threadIdx.x) * 4;
    const float* src; ushort* db; long o;
    if (idx < 9830400L) { src = f0; db = fab; o = idx; }
    else                { src = f1; db = fbb; o = idx - 9830400L; }
    float4 v = *(const float4*)&src[o];
    ushort4 u; u.x = f2b(v.x); u.y = f2b(v.y); u.z = f2b(v.z); u.w = f2b(v.w);
    *(ushort4*)&db[o] = u;
}

// ---------------- bf16 MFMA GEMM, 2-phase pipelined: C = act([A0|A1] @ Wt^T) -
// 128x128 tile, BK=32, double-buffered LDS, global_load_lds dwordx4,
// counted vmcnt(4) + raw s_barrier. LDS bank-swizzle on source col (rule #21).
// XCD-chunked remap (T1). TRANSPOSED-OPERAND epilogue: mfma(B,A) gives each
// lane 4 CONSECUTIVE cols of one row -> ushort4/float4 stores (4x fewer VMEM).
// Optional split output (Cb2/N2/colSplit): block-uniform dest select by n0.
__global__ __launch_bounds__(256) void lft_mfma_gemm(
    const ushort* __restrict__ A0, const ushort* __restrict__ A1, int kSplit,
    const ushort* __restrict__ Wt,
    float* Cf, ushort* Cb, int N, int K, int act, int actSplit,
    ushort* Cb2, int N2, int colSplit)
{
    __shared__ ushort As[2][128 * 32];
    __shared__ ushort Bs[2][128 * 32];
    int t = threadIdx.x;
    int nbx = gridDim.x;
    int nwg = nbx * gridDim.y;
    int orig = blockIdx.y * nbx + blockIdx.x;
    int q8 = nwg >> 3;
    int swz = (nwg & 7) ? orig : ((orig & 7) * q8 + (orig >> 3));
    int bx = swz % nbx, by = swz / nbx;
    int m0 = by << 7;
    int n0 = bx << 7;
    int wave = t >> 6, lane = t & 63;
    int wm = wave >> 1, wn = wave & 1;
    int l16 = lane & 15, quad = lane >> 4;
    int r = t >> 2;            // 0..63: row within half-tile
    int cu = (t & 3) << 3;     // linear LDS dest col offset (ushorts)
    int fso = (((t & 3) ^ ((r ^ (r >> 2)) & 3)) << 3);  // swizzled SOURCE col
    floatx4 acc[4][4] = {};

    auto stage = [&](int buf, int k0) {
        const ushort* Asrc; int kcol, ldA;
        if (k0 < kSplit) { Asrc = A0; kcol = k0;          ldA = kSplit; }
        else             { Asrc = A1; kcol = k0 - kSplit; ldA = K - kSplit; }
        gload_lds16(&Asrc[(size_t)(m0 + r) * ldA + kcol + fso],      &As[buf][r * 32 + cu]);
        gload_lds16(&Asrc[(size_t)(m0 + r + 64) * ldA + kcol + fso], &As[buf][(r + 64) * 32 + cu]);
        gload_lds16(&Wt[(size_t)(n0 + r) * K + k0 + fso],            &Bs[buf][r * 32 + cu]);
        gload_lds16(&Wt[(size_t)(n0 + r + 64) * K + k0 + fso],       &Bs[buf][(r + 64) * 32 + cu]);
    };

    int qs = ((quad ^ ((l16 ^ (l16 >> 2)) & 3)) << 3);  // swizzled READ col
    stage(0, 0);
    int cur = 0;
    for (int k0 = 0; k0 < K; k0 += 32) {
        if (k0 + 32 < K) {
            stage(cur ^ 1, k0 + 32);
            asm volatile("s_waitcnt vmcnt(4)" ::: "memory");
        } else {
            asm volatile("s_waitcnt vmcnt(0)" ::: "memory");
        }
        __builtin_amdgcn_s_barrier();
        short8 af[4], bfr[4];
#pragma unroll
        for (int i = 0; i < 4; i++) {
            af[i]  = *(const short8*)&As[cur][(wm * 64 + i * 16 + l16) * 32 + qs];
            bfr[i] = *(const short8*)&Bs[cur][(wn * 64 + i * 16 + l16) * 32 + qs];
        }
#pragma unroll
        for (int i = 0; i < 4; i++)
#pragma unroll
            for (int j = 0; j < 4; j++)
                acc[i][j] = __builtin_amdgcn_mfma_f32_16x16x32_bf16(bfr[j], af[i], acc[i][j], 0, 0, 0);
        asm volatile("" ::: "memory");
        __builtin_amdgcn_s_barrier();
        cur ^= 1;
    }
    int effAct = (n0 >= actSplit) ? 0 : act;
    float* Cfp = Cf;
    ushort* Cbp = Cb;
    int ldC = N, cb0 = n0;
    if (Cb2 && n0 >= colSplit) { Cbp = Cb2; Cfp = nullptr; ldC = N2; cb0 = n0 - colSplit; }
#pragma unroll
    for (int i = 0; i < 4; i++) {
        long rowb = m0 + wm * 64 + i * 16 + l16;
#pragma unroll
        for (int j = 0; j < 4; j++) {
            int colb = cb0 + wn * 64 + j * 16 + quad * 4;
            float v0 = acc[i][j][0], v1 = acc[i][j][1], v2 = acc[i][j][2], v3 = acc[i][j][3];
            if (effAct == 1) {
                v0 = v0 > 0.f ? v0 + 1.f : __expf(v0);
                v1 = v1 > 0.f ? v1 + 1.f : __expf(v1);
                v2 = v2 > 0.f ? v2 + 1.f : __expf(v2);
                v3 = v3 > 0.f ? v3 + 1.f : __expf(v3);
            } else if (effAct == 2) {
                v0 = fmaxf(v0, 0.f); v1 = fmaxf(v1, 0.f);
                v2 = fmaxf(v2, 0.f); v3 = fmaxf(v3, 0.f);
            }
            if (Cfp) {
                float4 f4; f4.x = v0; f4.y = v1; f4.z = v2; f4.w = v3;
                *(float4*)&Cfp[rowb * ldC + colb] = f4;
            }
            if (Cbp) {
                ushort4 u4;
                u4.x = f2b(v0); u4.y = f2b(v1); u4.z = f2b(v2); u4.w = f2b(v3);
                *(ushort4*)&Cbp[rowb * ldC + colb] = u4;
            }
        }
    }
}

// ---------------- fused GEMM (N=256 full-row) + LayerNorm epilogue -----------
// 128x256 tile, BK=32, 2x2 waves (32 MFMA/wave/step), same staging/swizzle as
// lft_mfma_gemm. Block owns FULL rows -> LN in epilogue: lane sum/sumsq over
// its 32 cols -> shfl over quad -> LDS exchange between col-half waves.
// Optional resid+cls (row passthrough when invalid), fp32+bf16 outputs.
__global__ __launch_bounds__(256, 2) void lft_gemm_ln(
    const ushort* __restrict__ A, const ushort* __restrict__ Wt, int K,
    const float* __restrict__ g, const float* __restrict__ bb,
    const float* __restrict__ resid, const int* __restrict__ cls,
    float* outF, ushort* __restrict__ outB)
{
    __shared__ ushort As[2][128 * 32];
    __shared__ ushort Bs[2][256 * 32];
    __shared__ float red[2][128][2];
    int t = threadIdx.x;
    long m0 = (long)blockIdx.x << 7;
    int wave = t >> 6, lane = t & 63;
    int wm = wave >> 1, wn = wave & 1;
    int l16 = lane & 15, quad = lane >> 4;
    int r = t >> 2;
    int cu = (t & 3) << 3;
    int fso = (((t & 3) ^ ((r ^ (r >> 2)) & 3)) << 3);
    floatx4 acc[4][8] = {};

    auto stage = [&](int buf, int k0) {
        gload_lds16(&A[(m0 + r) * K + k0 + fso],      &As[buf][r * 32 + cu]);
        gload_lds16(&A[(m0 + r + 64) * K + k0 + fso], &As[buf][(r + 64) * 32 + cu]);
#pragma unroll
        for (int i = 0; i < 4; i++)
            gload_lds16(&Wt[(size_t)(i * 64 + r) * K + k0 + fso],
                        &Bs[buf][(i * 64 + r) * 32 + cu]);
    };

    int qs = ((quad ^ ((l16 ^ (l16 >> 2)) & 3)) << 3);
    stage(0, 0);
    int cur = 0;
    for (int k0 = 0; k0 < K; k0 += 32) {
        if (k0 + 32 < K) {
            stage(cur ^ 1, k0 + 32);
            asm volatile("s_waitcnt vmcnt(6)" ::: "memory");
        } else {
            asm volatile("s_waitcnt vmcnt(0)" ::: "memory");
        }
        __builtin_amdgcn_s_barrier();
        short8 af[4], bfr[8];
#pragma unroll
        for (int i = 0; i < 4; i++)
            af[i]  = *(const short8*)&As[cur][(wm * 64 + i * 16 + l16) * 32 + qs];
#pragma unroll
        for (int j = 0; j < 8; j++)
            bfr[j] = *(const short8*)&Bs[cur][(wn * 128 + j * 16 + l16) * 32 + qs];
#pragma unroll
        for (int i = 0; i < 4; i++)
#pragma unroll
            for (int j = 0; j < 8; j++)
                acc[i][j] = __builtin_amdgcn_mfma_f32_16x16x32_bf16(bfr[j], af[i], acc[i][j], 0, 0, 0);
        asm volatile("" ::: "memory");
        __builtin_amdgcn_s_barrier();
        cur ^= 1;
    }
    // ---- row sums: lane covers 32 cols of its row; reduce over quad, then
    // exchange halves (wn) via LDS ----
#pragma unroll
    for (int i = 0; i < 4; i++) {
        float s = 0.f, sq = 0.f;
#pragma unroll
        for (int j = 0; j < 8; j++)
#pragma unroll
            for (int rr = 0; rr < 4; rr++) { float v = acc[i][j][rr]; s += v; sq += v * v; }
        s  += __shfl_xor(s, 16, 64);  sq += __shfl_xor(sq, 16, 64);
        s  += __shfl_xor(s, 32, 64);  sq += __shfl_xor(sq, 32, 64);
        if (quad == 0) {
            int rl = wm * 64 + i * 16 + l16;
            red[wn][rl][0] = s;
            red[wn][rl][1] = sq;
        }
    }
    __syncthreads();
#pragma unroll
    for (int i = 0; i < 4; i++) {
        int rl = wm * 64 + i * 16 + l16;
        long row = m0 + rl;
        float tsum = red[0][rl][0] + red[1][rl][0];
        float tsq  = red[0][rl][1] + red[1][rl][1];
        float mean = tsum * (1.0f / 256.0f);
        float var  = tsq * (1.0f / 256.0f) - mean * mean;
        float rsq  = rsqrtf(var + 1e-5f);
        bool keep = true;
        if (cls) keep = (cls[row] >= 0);
#pragma unroll
        for (int j = 0; j < 8; j++) {
            int col = wn * 128 + j * 16 + quad * 4;
            float4 gv = *(const float4*)&g[col];
            float4 bv = *(const float4*)&bb[col];
            float y0 = (acc[i][j][0] - mean) * rsq * gv.x + bv.x;
            float y1 = (acc[i][j][1] - mean) * rsq * gv.y + bv.y;
            float y2 = (acc[i][j][2] - mean) * rsq * gv.z + bv.z;
            float y3 = (acc[i][j][3] - mean) * rsq * gv.w + bv.w;
            if (resid) {
                float4 xr = *(const float4*)&resid[row * 256 + col];
                if (keep) { y0 += xr.x; y1 += xr.y; y2 += xr.z; y3 += xr.w; }
                else      { y0 = xr.x;  y1 = xr.y;  y2 = xr.z;  y3 = xr.w; }
            }
            if (outF) {
                float4 f4; f4.x = y0; f4.y = y1; f4.z = y2; f4.w = y3;
                *(float4*)&outF[row * 256 + col] = f4;
            }
            ushort4 u4;
            u4.x = f2b(y0); u4.y = f2b(y1); u4.z = f2b(y2); u4.w = f2b(y3);
            *(ushort4*)&outB[row * 256 + col] = u4;
        }
    }
}

// ---------------- per-class KV / Ksum reduction (SRC-side token lists) --------
// kvab: fused bf16 [38400][512], cols 0..255 = phi_k, 256..511 = v
__global__ __launch_bounds__(256) void lft_kv_kernel(
    const ushort* __restrict__ kvab,
    const int* __restrict__ tlist, const int* __restrict__ meta,
    float* kv, float* ksum)
{
    int chunk = blockIdx.x, c = blockIdx.y;
    int b = blockIdx.z >> 3, h = blockIdx.z & 7;
    int off = meta[(b * 8 + c) * 2], n = meta[(b * 8 + c) * 2 + 1];
    int per = (n + KV_NCH - 1) / KV_NCH;
    int s0 = chunk * per;
    int s1 = min(s0 + per, n);
    if (s0 >= s1) return;
    const int* tl = tlist + b * 4800 + off;
    int t = threadIdx.x;
    __shared__ float kb[8][32];
    __shared__ float vb[8][32];
    int od = t >> 3, oe = (t & 7) << 2;
    int lt = t >> 5, ld = t & 31;
    float a0 = 0.f, a1 = 0.f, a2 = 0.f, a3 = 0.f, ak = 0.f;
    for (int s = s0; s < s1; s += 8) {
        float kval = 0.f, vval = 0.f;
        if (s + lt < s1) {
            int tok = tl[s + lt];
            long bse = ((long)b * 4800 + tok) * 512 + h * 32 + ld;
            kval = b2f(kvab[bse]);
            vval = b2f(kvab[bse + 256]);
        }
        __syncthreads();
        kb[lt][ld] = kval;
        vb[lt][ld] = vval;
        __syncthreads();
#pragma unroll
        for (int j = 0; j < 8; j++) {
            float kd = kb[j][od];
            float4 vv = *(const float4*)&vb[j][oe];
            a0 += kd * vv.x; a1 += kd * vv.y; a2 += kd * vv.z; a3 += kd * vv.w;
            ak += kd;
        }
    }
    float* dst = kv + (((long)(b * NPROTO + c) * 8 + h) << 10) + od * 32 + oe;
    atomicAdd(dst + 0, a0);
    atomicAdd(dst + 1, a1);
    atomicAdd(dst + 2, a2);
    atomicAdd(dst + 3, a3);
    if ((t & 7) == 0)
        atomicAdd(ksum + (((long)(b * NPROTO + c) * 8 + h) << 5) + od, ak);
}

// ---------------- kv fp32 [d][e] + ksum → bf16 B-layout [e'][d], e'<48 -------
__global__ __launch_bounds__(256) void lft_kvconv_kernel(
    const float* __restrict__ kvb, const float* __restrict__ ksb,
    ushort* __restrict__ kvt)
{
    int bc = blockIdx.x;          // b*8+c
    int t = threadIdx.x;
    int h = t >> 5, d = t & 31;
    const float* kvsrc = kvb + ((long)bc * 8 + h) * 1024;
    const float* kssrc = ksb + ((long)bc * 8 + h) * 32;
    ushort* dst = kvt + ((long)bc * 8 + h) * 1536;
#pragma unroll
    for (int e = 0; e < 32; e++) dst[e * 32 + d] = f2b(kvsrc[d * 32 + e]);
    dst[32 * 32 + d] = f2b(kssrc[d]);
#pragma unroll
    for (int e = 33; e < 48; e++) dst[e * 32 + d] = 0;
}

// ---------------- msg via MFMA over X-SIDE class-sorted lists ----------------
__global__ __launch_bounds__(256) void lft_msg_kernel(
    const ushort* __restrict__ pq, const ushort* __restrict__ kvt,
    const int* __restrict__ tlist, const int* __restrict__ meta,
    ushort* __restrict__ msg)
{
    int chunk = blockIdx.x, c = blockIdx.y, b = blockIdx.z;
    int off = meta[(b * 8 + c) * 2], n = meta[(b * 8 + c) * 2 + 1];
    int per = (n + MSG_NCH - 1) / MSG_NCH;
    int s0 = chunk * per, s1 = min(s0 + per, n);
    if (s0 >= s1) return;
    const int* tl = tlist + b * 4800 + off;
    int t = threadIdx.x;
    int wave = t >> 6, lane = t & 63;
    int l16 = lane & 15, quad = lane >> 4;
    int bc = b * 8 + c;
    short8 bfr[2][3];
#pragma unroll
    for (int hh = 0; hh < 2; hh++) {
        int h = wave * 2 + hh;
        const ushort* kb = kvt + ((long)bc * 8 + h) * 1536;
#pragma unroll
        for (int nt = 0; nt < 3; nt++)
            bfr[hh][nt] = *(const short8*)&kb[(nt * 16 + l16) * 32 + quad * 8];
    }
    for (int s = s0; s < s1; s += 16) {
        int ia = min(s + l16, s1 - 1);
        int tokA = tl[ia];
        long rowA = (long)b * 4800 + tokA;
#pragma unroll
        for (int hh = 0; hh < 2; hh++) {
            int h = wave * 2 + hh;
            short8 a = *(const short8*)&pq[rowA * 256 + h * 32 + quad * 8];
            floatx4 n0 = {}, n1 = {}, dd = {};
            n0 = __builtin_amdgcn_mfma_f32_16x16x32_bf16(a, bfr[hh][0], n0, 0, 0, 0);
            n1 = __builtin_amdgcn_mfma_f32_16x16x32_bf16(a, bfr[hh][1], n1, 0, 0, 0);
            dd = __builtin_amdgcn_mfma_f32_16x16x32_bf16(a, bfr[hh][2], dd, 0, 0, 0);
#pragma unroll
            for (int r = 0; r < 4; r++) {
                int rowi = s + quad * 4 + r;
                float den = __shfl(dd[r], lane & 48, 64);
                float inv = 1.f / (den + 1e-6f);
                int tokr = __shfl(tokA, quad * 4 + r, 64);
                if (rowi < s1) {
                    long base = ((long)b * 4800 + tokr) * 256 + h * 32;
                    msg[base + l16]      = f2b(n0[r] * inv);
                    msg[base + 16 + l16] = f2b(n1[r] * inv);
                }
            }
        }
    }
}

extern "C" void kernel_launch(void* const* d_in, const int* in_sizes, int n_in,
                              void* d_out, int out_size, void* d_ws, size_t ws_size,
                              hipStream_t stream)
{
    (void)in_sizes; (void)n_in; (void)out_size; (void)ws_size;
    const float* feat0 = (const float*)d_in[0];
    const float* feat1 = (const float*)d_in[1];
    const int*   mask0 = (const int*)d_in[2];
    const int*   mask1 = (const int*)d_in[3];
    const float* f0wo  = (const float*)d_in[4];
    const float* f1wo  = (const float*)d_in[5];
    const float* proto = (const float*)d_in[6];
    const float* Wq = (const float*)d_in[7];
    const float* Wk = (const float*)d_in[8];
    const float* Wv = (const float*)d_in[9];
    const float* Wm = (const float*)d_in[10];
    const float* W1 = (const float*)d_in[11];
    const float* W2 = (const float*)d_in[12];
    const float* g1 = (const float*)d_in[13];
    const float* b1 = (const float*)d_in[14];
    const float* g2 = (const float*)d_in[15];
    const float* b2 = (const float*)d_in[16];
    float* out = (float*)d_out;
    float* ws = (float*)d_ws;

    // ---- workspace layout ----
    const long FSZ = 9830400L;           // 8*4800*256
    float* fa   = ws;                    // fp32 master feat0
    float* fb   = ws + FSZ;              // fp32 master feat1
    float* vbuf = ws + 3 * FSZ;          // bf16 [38400][512]: kv fused out, later hid
    ushort* ub  = (ushort*)(ws + 4 * FSZ);
    ushort* fa_bf  = ub;                 // bf16 shadow of fa
    ushort* fb_bf  = ub + FSZ;           // bf16 shadow of fb
    ushort* msg_bf = ub + 2 * FSZ;       // msg bf16; later LN1 bf16 out (in-place)
    ushort* qb_bf  = ub + 3 * FSZ;       // phi_q bf16
    ushort* wb     = ub + 4 * FSZ;       // bf16 transposed weights
    ushort* wb1    = wb + 16 * 65536;    // W1^T per layer [512][512]
    ushort* wb2    = wb1 + 4 * 262144;   // W2^T per layer [256][512]
    ushort* kvt    = wb2 + 4 * 131072;   // [64][8][48][32] bf16
    float* kvb = (float*)(kvt + 786432); // [B,NP,H,D,D] = 524288 f
    float* ksb = kvb + 524288;           // [B,NP,H,D]   = 16384 f
    int* cls0 = (int*)(ksb + 16384);
    int* cls1 = cls0 + 38400;
    int* tl0  = cls1 + 38400;            // class-sorted token lists
    int* tl1  = tl0 + 38400;
    int* meta = tl1 + 38400;             // [2][8][8][2] (off,cnt)
    ushort* kvab   = (ushort*)vbuf;      // [38400,512] bf16: [phi_k | v]
    ushort* hid_bf = (ushort*)vbuf;      // [38400,512] bf16 (after kv consumed)

    // one-time per launch
    lft_wconv_kernel<<<dim3(8, 8, 16), 256, 0, stream>>>(Wq, Wk, Wv, Wm, 256, 256, 4, wb);
    lft_wconv_kernel<<<dim3(16, 16, 4), 256, 0, stream>>>(W1, W1, W1, W1, 512, 512, 1, wb1);
    lft_wconv_kernel<<<dim3(16, 8, 4), 256, 0, stream>>>(W2, W2, W2, W2, 512, 256, 1, wb2);
    lft_cast_kernel<<<19200, 256, 0, stream>>>(feat0, feat1, fa_bf, fb_bf);
    hipMemcpyAsync(out + 20352000L, proto, 2048 * 4, hipMemcpyDeviceToDevice, stream);
    lft_class_kernel<<<19200, 256, 0, stream>>>(f0wo, f1wo, mask0, mask1, proto,
                                                out, cls0, cls1);
    lft_sort_kernel<<<16, 256, 0, stream>>>(cls0, cls1, tl0, tl1, meta);

    for (int li = 0; li < 4; li++) {
        const ushort* wq = wb + (size_t)(li * 4 + 0) * 65536;  // wq|wk|wv contig: [768][256]
        const ushort* wk = wb + (size_t)(li * 4 + 1) * 65536;  // wk|wv contiguous: [512][256]
        const ushort* wm = wb + (size_t)(li * 4 + 3) * 65536;
        const ushort* w1 = wb1 + (size_t)li * 262144;
        const ushort* w2 = wb2 + (size_t)li * 131072;
        const float* g1p = g1 + li * 256; const float* b1p = b1 + li * 256;
        const float* g2p = g2 + li * 256; const float* b2p = b2 + li * 256;

        auto call = [&](ushort* x_bf, ushort* s_bf, const int* clsx,
                        const int* tlx, const int* mtx,
                        const int* tls, const int* mts,
                        const float* residp, float* outFp) {
            dim3 blk(256);
            dim3 gA(2, 300), gB(4, 300), gQ(6, 300);
            if (x_bf == s_bf) {
                // self-self: fused [q|phi_k|v] = x@[Wq|Wk|Wv], N=768, split out:
                // cols<256 -> qb_bf (N=256), cols>=256 -> kvab (N=512)
                lft_mfma_gemm<<<gQ, blk, 0, stream>>>(x_bf, x_bf, 256, wq,
                    nullptr, qb_bf, 256, 256, 1, 512, kvab, 512, 256);
            } else {
                lft_mfma_gemm<<<gA, blk, 0, stream>>>(x_bf, x_bf, 256, wq,
                    nullptr, qb_bf, 256, 256, 1, 256, nullptr, 0, 0);
                lft_mfma_gemm<<<gB, blk, 0, stream>>>(s_bf, s_bf, 256, wk,
                    nullptr, kvab, 512, 256, 1, 256, nullptr, 0, 0);
            }
            hipMemsetAsync(kvb, 0, (524288 + 16384) * 4, stream);
            lft_kv_kernel<<<dim3(KV_NCH, 8, 64), blk, 0, stream>>>(kvab, tls, mts, kvb, ksb);
            lft_kvconv_kernel<<<64, blk, 0, stream>>>(kvb, ksb, kvt);
            lft_msg_kernel<<<dim3(MSG_NCH, 8, 8), blk, 0, stream>>>(qb_bf, kvt, tlx, mtx, msg_bf);
            // msg = LN(msg @ Wm)*g1+b1 -- fused GEMM+LN, bf16 out in-place
            // (each block reads only its own A-rows; write after full consume)
            lft_gemm_ln<<<300, blk, 0, stream>>>(msg_bf, wm, 256, g1p, b1p,
                                                 nullptr, nullptr, nullptr, msg_bf);
            // hid = relu([x|msg]@W1) bf16
            lft_mfma_gemm<<<gB, blk, 0, stream>>>(x_bf, msg_bf, 256, w1,
                nullptr, hid_bf, 512, 512, 2, 512, nullptr, 0, 0);
            // out = valid ? resid + LN(hid@W2) : resid -- fused GEMM+LN+resid
            lft_gemm_ln<<<300, blk, 0, stream>>>(hid_bf, w2, 512, g2p, b2p,
                                                 residp, clsx, outFp, x_bf);
        };

        const float* ra = (li == 0) ? feat0 : fa;
        const float* rb = (li == 0) ? feat1 : fb;
        float* oa = (li == 3) ? out : fa;
        float* ob = (li == 3) ? (out + FSZ) : fb;

        if ((li & 1) == 0) {           // self-self
            call(fa_bf, fa_bf, cls0, tl0, meta,       tl0, meta,       ra, oa);
            call(fb_bf, fb_bf, cls1, tl1, meta + 128, tl1, meta + 128, rb, ob);
        } else {                       // cross-self: x=feat0 iterates tl0, gathers tl1
            call(fa_bf, fb_bf, cls0, tl0, meta,       tl1, meta + 128, ra, oa);
            call(fb_bf, fa_bf, cls1, tl1, meta + 128, tl0, meta,      rb, ob);
        }
    }
}

// Round 11
// 1645.987 us; speedup vs baseline: 1.0766x; 1.0105x over previous
//
#include <hip/hip_runtime.h>
#include <math.h>

#define NPROTO 8
#define KV_NCH 4
#define MSG_NCH 8

typedef __attribute__((ext_vector_type(8))) short short8;
typedef __attribute__((ext_vector_type(4))) float floatx4;

static __device__ __forceinline__ ushort f2b(float f) {
    unsigned u = __builtin_bit_cast(unsigned, f);
    unsigned r = (u + 0x7fffu + ((u >> 16) & 1u)) >> 16;
    return (ushort)r;
}

static __device__ __forceinline__ float b2f(ushort u) {
    return __builtin_bit_cast(float, ((unsigned)u) << 16);
}

typedef __attribute__((address_space(1))) void gvoid;
typedef __attribute__((address_space(3))) void lvoid;

// async global->LDS, 16B per lane. LDS dest must be lane-contiguous per wave.
static __device__ __forceinline__ void gload_lds16(const ushort* g, ushort* l) {
    __builtin_amdgcn_global_load_lds((gvoid*)(void*)g, (lvoid*)l, 16, 0, 0);
}

// ---------------- prototype projection / argmax-class kernel ----------------
__global__ __launch_bounds__(256) void lft_class_kernel(
    const float* __restrict__ f0wo, const float* __restrict__ f1wo,
    const int* __restrict__ mask0, const int* __restrict__ mask1,
    const float* __restrict__ proto,
    float* out, int* cls0, int* cls1)
{
    __shared__ float pr[2048];
    int t = threadIdx.x;
    *(float4*)&pr[t * 4]        = *(const float4*)&proto[t * 4];
    *(float4*)&pr[1024 + t * 4] = *(const float4*)&proto[1024 + t * 4];
    __syncthreads();
    int wave = t >> 6, lane = t & 63;
    long token = (long)blockIdx.x * 4 + wave;
    const float* fsrc; const int* msrc; float* fpout; float* clsout; int* clsarr; long tok;
    if (token < 38400) {
        tok = token; fsrc = f0wo; msrc = mask0;
        fpout = out + 19737600L; clsout = out + 19660800L; clsarr = cls0;
    } else {
        tok = token - 38400; fsrc = f1wo; msrc = mask1;
        fpout = out + 20044800L; clsout = out + 19699200L; clsarr = cls1;
    }
    float4 f = *(const float4*)&fsrc[tok * 256 + lane * 4];
    float s[NPROTO];
#pragma unroll
    for (int p = 0; p < NPROTO; p++) {
        float4 pv = *(const float4*)&pr[p * 256 + lane * 4];
        s[p] = f.x * pv.x + f.y * pv.y + f.z * pv.z + f.w * pv.w;
    }
    float k0_ = (lane & 1) ? s[4] : s[0], d0 = (lane & 1) ? s[0] : s[4];
    float k1_ = (lane & 1) ? s[5] : s[1], d1 = (lane & 1) ? s[1] : s[5];
    float k2_ = (lane & 1) ? s[6] : s[2], d2 = (lane & 1) ? s[2] : s[6];
    float k3_ = (lane & 1) ? s[7] : s[3], d3 = (lane & 1) ? s[3] : s[7];
    float w0 = k0_ + __shfl_xor(d0, 1, 64);
    float w1 = k1_ + __shfl_xor(d1, 1, 64);
    float w2 = k2_ + __shfl_xor(d2, 1, 64);
    float w3 = k3_ + __shfl_xor(d3, 1, 64);
    float u0k = (lane & 2) ? w2 : w0, u0d = (lane & 2) ? w0 : w2;
    float u1k = (lane & 2) ? w3 : w1, u1d = (lane & 2) ? w1 : w3;
    float x0 = u0k + __shfl_xor(u0d, 2, 64);
    float x1 = u1k + __shfl_xor(u1d, 2, 64);
    float yk = (lane & 4) ? x1 : x0, yd = (lane & 4) ? x0 : x1;
    float sc = yk + __shfl_xor(yd, 4, 64);
    sc += __shfl_xor(sc, 8, 64);
    sc += __shfl_xor(sc, 16, 64);
    sc += __shfl_xor(sc, 32, 64);
    int p = ((lane & 1) << 2) | (lane & 2) | ((lane >> 2) & 1);
    if (lane < 8) fpout[tok * 8 + p] = sc;
    float bv = sc; int bi = p;
#pragma unroll
    for (int o = 1; o < 8; o <<= 1) {
        float ov = __shfl_xor(bv, o, 64);
        int oi = __shfl_xor(bi, o, 64);
        if (ov > bv || (ov == bv && oi < bi)) { bv = ov; bi = oi; }
    }
    if (lane == 0) {
        clsout[tok] = (float)bi;
        clsarr[tok] = msrc[tok] ? bi : -1;
    }
}

// ---------------- counting sort of tokens by (batch,class) -------------------
__global__ __launch_bounds__(256) void lft_sort_kernel(
    const int* __restrict__ cls0, const int* __restrict__ cls1,
    int* tl0, int* tl1, int* meta)
{
    int g = blockIdx.x; int L = g >> 3, b = g & 7;
    const int* cls = (L ? cls1 : cls0) + b * 4800;
    int* tl = (L ? tl1 : tl0) + b * 4800;
    int* mt = meta + (L * 8 + b) * 16;
    __shared__ int cnt[8], base[8], pos[8];
    int t = threadIdx.x;
    if (t < 8) cnt[t] = 0;
    __syncthreads();
    for (int tok = t; tok < 4800; tok += 256) {
        int c = cls[tok];
        if (c >= 0) atomicAdd(&cnt[c], 1);
    }
    __syncthreads();
    if (t == 0) {
        int s = 0;
        for (int c = 0; c < 8; c++) { base[c] = s; pos[c] = s; s += cnt[c]; }
    }
    __syncthreads();
    if (t < 8) { mt[t * 2] = base[t]; mt[t * 2 + 1] = cnt[t]; }
    for (int tok = t; tok < 4800; tok += 256) {
        int c = cls[tok];
        if (c >= 0) { int p = atomicAdd(&pos[c], 1); tl[p] = tok; }
    }
}

// ---------------- weight convert + transpose: Wt[n*K+k] = bf16(W[k*N+n]) ----
__global__ __launch_bounds__(256) void lft_wconv_kernel(
    const float* W0, const float* W1p, const float* W2p, const float* W3p,
    int K, int N, int nTypes, ushort* dst)
{
    int z = blockIdx.z;
    int li = z / nTypes, mi = z % nTypes;
    const float* srcs[4] = {W0, W1p, W2p, W3p};
    const float* src = srcs[mi] + (size_t)li * K * N;
    ushort* outp = dst + (size_t)z * K * N;
    __shared__ float tile[32][33];
    int k0 = blockIdx.x * 32, n0 = blockIdx.y * 32;
    int t = threadIdx.x;
    int r = t >> 3, c4 = (t & 7) << 2;
    float4 v = *(const float4*)&src[(size_t)(k0 + r) * N + n0 + c4];
    tile[r][c4] = v.x; tile[r][c4 + 1] = v.y; tile[r][c4 + 2] = v.z; tile[r][c4 + 3] = v.w;
    __syncthreads();
    ushort4 o;
    o.x = f2b(tile[c4 + 0][r]);
    o.y = f2b(tile[c4 + 1][r]);
    o.z = f2b(tile[c4 + 2][r]);
    o.w = f2b(tile[c4 + 3][r]);
    *(ushort4*)&outp[(size_t)(n0 + r) * K + k0 + c4] = o;
}

// ---------------- bf16 cast of feat0/feat1 (shadows only) ----------------
__global__ __launch_bounds__(256) void lft_cast_kernel(
    const float* __restrict__ f0, const float* __restrict__ f1,
    ushort* fab, ushort* fbb)
{
    long idx = ((long)blockIdx.x * 256 + threadIdx.x) * 4;
    const float* src; ushort* db; long o;
    if (idx < 9830400L) { src = f0; db = fab; o = idx; }
    else                { src = f1; db = fbb; o = idx - 9830400L; }
    float4 v = *(const float4*)&src[o];
    ushort4 u; u.x = f2b(v.x); u.y = f2b(v.y); u.z = f2b(v.z); u.w = f2b(v.w);
    *(ushort4*)&db[o] = u;
}

// ---------------- bf16 MFMA GEMM, 2-phase pipelined: C = act([A0|A1] @ Wt^T) -
// 128x128 tile, BK=32, double-buffered LDS, global_load_lds dwordx4,
// counted vmcnt(4) + raw s_barrier. LDS bank-swizzle on source col (rule #21).
// XCD-chunked remap (T1). TRANSPOSED-OPERAND epilogue: mfma(B,A) gives each
// lane 4 CONSECUTIVE cols of one row -> ushort4/float4 stores.
// Optional split output (Cb2/N2/colSplit): block-uniform dest select by n0.
__global__ __launch_bounds__(256) void lft_mfma_gemm(
    const ushort* __restrict__ A0, const ushort* __restrict__ A1, int kSplit,
    const ushort* __restrict__ Wt,
    float* Cf, ushort* Cb, int N, int K, int act, int actSplit,
    ushort* Cb2, int N2, int colSplit)
{
    __shared__ ushort As[2][128 * 32];
    __shared__ ushort Bs[2][128 * 32];
    int t = threadIdx.x;
    int nbx = gridDim.x;
    int nwg = nbx * gridDim.y;
    int orig = blockIdx.y * nbx + blockIdx.x;
    int q8 = nwg >> 3;
    int swz = (nwg & 7) ? orig : ((orig & 7) * q8 + (orig >> 3));
    int bx = swz % nbx, by = swz / nbx;
    int m0 = by << 7;
    int n0 = bx << 7;
    int wave = t >> 6, lane = t & 63;
    int wm = wave >> 1, wn = wave & 1;
    int l16 = lane & 15, quad = lane >> 4;
    int r = t >> 2;            // 0..63: row within half-tile
    int cu = (t & 3) << 3;     // linear LDS dest col offset (ushorts)
    int fso = (((t & 3) ^ ((r ^ (r >> 2)) & 3)) << 3);  // swizzled SOURCE col
    floatx4 acc[4][4] = {};

    auto stage = [&](int buf, int k0) {
        const ushort* Asrc; int kcol, ldA;
        if (k0 < kSplit) { Asrc = A0; kcol = k0;          ldA = kSplit; }
        else             { Asrc = A1; kcol = k0 - kSplit; ldA = K - kSplit; }
        gload_lds16(&Asrc[(size_t)(m0 + r) * ldA + kcol + fso],      &As[buf][r * 32 + cu]);
        gload_lds16(&Asrc[(size_t)(m0 + r + 64) * ldA + kcol + fso], &As[buf][(r + 64) * 32 + cu]);
        gload_lds16(&Wt[(size_t)(n0 + r) * K + k0 + fso],            &Bs[buf][r * 32 + cu]);
        gload_lds16(&Wt[(size_t)(n0 + r + 64) * K + k0 + fso],       &Bs[buf][(r + 64) * 32 + cu]);
    };

    int qs = ((quad ^ ((l16 ^ (l16 >> 2)) & 3)) << 3);  // swizzled READ col
    stage(0, 0);
    int cur = 0;
    for (int k0 = 0; k0 < K; k0 += 32) {
        if (k0 + 32 < K) {
            stage(cur ^ 1, k0 + 32);
            asm volatile("s_waitcnt vmcnt(4)" ::: "memory");
        } else {
            asm volatile("s_waitcnt vmcnt(0)" ::: "memory");
        }
        __builtin_amdgcn_s_barrier();
        short8 af[4], bfr[4];
#pragma unroll
        for (int i = 0; i < 4; i++) {
            af[i]  = *(const short8*)&As[cur][(wm * 64 + i * 16 + l16) * 32 + qs];
            bfr[i] = *(const short8*)&Bs[cur][(wn * 64 + i * 16 + l16) * 32 + qs];
        }
#pragma unroll
        for (int i = 0; i < 4; i++)
#pragma unroll
            for (int j = 0; j < 4; j++)
                acc[i][j] = __builtin_amdgcn_mfma_f32_16x16x32_bf16(bfr[j], af[i], acc[i][j], 0, 0, 0);
        asm volatile("" ::: "memory");
        __builtin_amdgcn_s_barrier();
        cur ^= 1;
    }
    int effAct = (n0 >= actSplit) ? 0 : act;
    float* Cfp = Cf;
    ushort* Cbp = Cb;
    int ldC = N, cb0 = n0;
    if (Cb2 && n0 >= colSplit) { Cbp = Cb2; Cfp = nullptr; ldC = N2; cb0 = n0 - colSplit; }
#pragma unroll
    for (int i = 0; i < 4; i++) {
        long rowb = m0 + wm * 64 + i * 16 + l16;
#pragma unroll
        for (int j = 0; j < 4; j++) {
            int colb = cb0 + wn * 64 + j * 16 + quad * 4;
            float v0 = acc[i][j][0], v1 = acc[i][j][1], v2 = acc[i][j][2], v3 = acc[i][j][3];
            if (effAct == 1) {
                v0 = v0 > 0.f ? v0 + 1.f : __expf(v0);
                v1 = v1 > 0.f ? v1 + 1.f : __expf(v1);
                v2 = v2 > 0.f ? v2 + 1.f : __expf(v2);
                v3 = v3 > 0.f ? v3 + 1.f : __expf(v3);
            } else if (effAct == 2) {
                v0 = fmaxf(v0, 0.f); v1 = fmaxf(v1, 0.f);
                v2 = fmaxf(v2, 0.f); v3 = fmaxf(v3, 0.f);
            }
            if (Cfp) {
                float4 f4; f4.x = v0; f4.y = v1; f4.z = v2; f4.w = v3;
                *(float4*)&Cfp[rowb * ldC + colb] = f4;
            }
            if (Cbp) {
                ushort4 u4;
                u4.x = f2b(v0); u4.y = f2b(v1); u4.z = f2b(v2); u4.w = f2b(v3);
                *(ushort4*)&Cbp[rowb * ldC + colb] = u4;
            }
        }
    }
}

// ---------------- fused GEMM (N=256 full-row) + LayerNorm epilogue -----------
// 128x256 tile, BK=32, 512 threads / 8 waves (2 row-halves x 4 col-quarters):
// each wave = 64x64 sub-tile, 16 MFMA + 8 ds_read per K-step (same per-wave
// shape as lft_mfma_gemm). 3 gload_lds16/thread/step, counted vmcnt(3).
// Block owns FULL rows -> LN in epilogue via quad-shfl + red[4][128] combine.
__global__ __launch_bounds__(512) void lft_gemm_ln(
    const ushort* __restrict__ A, const ushort* __restrict__ Wt, int K,
    const float* __restrict__ g, const float* __restrict__ bb,
    const float* __restrict__ resid, const int* __restrict__ cls,
    float* outF, ushort* __restrict__ outB)
{
    __shared__ ushort As[2][128 * 32];
    __shared__ ushort Bs[2][256 * 32];
    __shared__ float red[4][128][2];
    int t = threadIdx.x;                  // 0..511
    long m0 = (long)blockIdx.x << 7;
    int wave = t >> 6, lane = t & 63;
    int wm = wave >> 2, wn = wave & 3;    // 2 x 4 wave grid
    int l16 = lane & 15, quad = lane >> 4;
    int r = t >> 2;                       // 0..127 (A row / B row-low)
    int cu = (t & 3) << 3;
    int fso = (((t & 3) ^ ((r ^ (r >> 2)) & 3)) << 3);
    // B row r+128: ((r+128)^((r+128)>>2))&3 == (r^(r>>2))&3  (128 % 4 == 0 in both terms)
    floatx4 acc[4][4] = {};

    auto stage = [&](int buf, int k0) {
        gload_lds16(&A[(m0 + r) * K + k0 + fso],              &As[buf][r * 32 + cu]);
        gload_lds16(&Wt[(size_t)r * K + k0 + fso],            &Bs[buf][r * 32 + cu]);
        gload_lds16(&Wt[(size_t)(r + 128) * K + k0 + fso],    &Bs[buf][(r + 128) * 32 + cu]);
    };

    int qs = ((quad ^ ((l16 ^ (l16 >> 2)) & 3)) << 3);
    stage(0, 0);
    int cur = 0;
    for (int k0 = 0; k0 < K; k0 += 32) {
        if (k0 + 32 < K) {
            stage(cur ^ 1, k0 + 32);
            asm volatile("s_waitcnt vmcnt(3)" ::: "memory");
        } else {
            asm volatile("s_waitcnt vmcnt(0)" ::: "memory");
        }
        __builtin_amdgcn_s_barrier();
        short8 af[4], bfr[4];
#pragma unroll
        for (int i = 0; i < 4; i++) {
            af[i]  = *(const short8*)&As[cur][(wm * 64 + i * 16 + l16) * 32 + qs];
            bfr[i] = *(const short8*)&Bs[cur][(wn * 64 + i * 16 + l16) * 32 + qs];
        }
        // transposed-operand: lane l16 = row (m-local), quad*4+rr = 4 consec cols
#pragma unroll
        for (int i = 0; i < 4; i++)
#pragma unroll
            for (int j = 0; j < 4; j++)
                acc[i][j] = __builtin_amdgcn_mfma_f32_16x16x32_bf16(bfr[j], af[i], acc[i][j], 0, 0, 0);
        asm volatile("" ::: "memory");
        __builtin_amdgcn_s_barrier();
        cur ^= 1;
    }
    // ---- row sums: lane covers 16 cols of each of its 4 row-frags; reduce
    // over quad (shfl), then combine the 4 col-quarter waves via LDS ----
#pragma unroll
    for (int i = 0; i < 4; i++) {
        float s = 0.f, sq = 0.f;
#pragma unroll
        for (int j = 0; j < 4; j++)
#pragma unroll
            for (int rr = 0; rr < 4; rr++) { float v = acc[i][j][rr]; s += v; sq += v * v; }
        s  += __shfl_xor(s, 16, 64);  sq += __shfl_xor(sq, 16, 64);
        s  += __shfl_xor(s, 32, 64);  sq += __shfl_xor(sq, 32, 64);
        if (quad == 0) {
            int rl = wm * 64 + i * 16 + l16;
            red[wn][rl][0] = s;
            red[wn][rl][1] = sq;
        }
    }
    __syncthreads();
#pragma unroll
    for (int i = 0; i < 4; i++) {
        int rl = wm * 64 + i * 16 + l16;
        long row = m0 + rl;
        float tsum = red[0][rl][0] + red[1][rl][0] + red[2][rl][0] + red[3][rl][0];
        float tsq  = red[0][rl][1] + red[1][rl][1] + red[2][rl][1] + red[3][rl][1];
        float mean = tsum * (1.0f / 256.0f);
        float var  = tsq * (1.0f / 256.0f) - mean * mean;
        float rsq  = rsqrtf(var + 1e-5f);
        bool keep = true;
        if (cls) keep = (cls[row] >= 0);
#pragma unroll
        for (int j = 0; j < 4; j++) {
            int col = wn * 64 + j * 16 + quad * 4;
            float4 gv = *(const float4*)&g[col];
            float4 bv = *(const float4*)&bb[col];
            float y0 = (acc[i][j][0] - mean) * rsq * gv.x + bv.x;
            float y1 = (acc[i][j][1] - mean) * rsq * gv.y + bv.y;
            float y2 = (acc[i][j][2] - mean) * rsq * gv.z + bv.z;
            float y3 = (acc[i][j][3] - mean) * rsq * gv.w + bv.w;
            if (resid) {
                float4 xr = *(const float4*)&resid[row * 256 + col];
                if (keep) { y0 += xr.x; y1 += xr.y; y2 += xr.z; y3 += xr.w; }
                else      { y0 = xr.x;  y1 = xr.y;  y2 = xr.z;  y3 = xr.w; }
            }
            if (outF) {
                float4 f4; f4.x = y0; f4.y = y1; f4.z = y2; f4.w = y3;
                *(float4*)&outF[row * 256 + col] = f4;
            }
            ushort4 u4;
            u4.x = f2b(y0); u4.y = f2b(y1); u4.z = f2b(y2); u4.w = f2b(y3);
            *(ushort4*)&outB[row * 256 + col] = u4;
        }
    }
}

// ---------------- per-class KV / Ksum reduction (SRC-side token lists) --------
// kvab: fused bf16 [38400][512], cols 0..255 = phi_k, 256..511 = v
__global__ __launch_bounds__(256) void lft_kv_kernel(
    const ushort* __restrict__ kvab,
    const int* __restrict__ tlist, const int* __restrict__ meta,
    float* kv, float* ksum)
{
    int chunk = blockIdx.x, c = blockIdx.y;
    int b = blockIdx.z >> 3, h = blockIdx.z & 7;
    int off = meta[(b * 8 + c) * 2], n = meta[(b * 8 + c) * 2 + 1];
    int per = (n + KV_NCH - 1) / KV_NCH;
    int s0 = chunk * per;
    int s1 = min(s0 + per, n);
    if (s0 >= s1) return;
    const int* tl = tlist + b * 4800 + off;
    int t = threadIdx.x;
    __shared__ float kb[8][32];
    __shared__ float vb[8][32];
    int od = t >> 3, oe = (t & 7) << 2;
    int lt = t >> 5, ld = t & 31;
    float a0 = 0.f, a1 = 0.f, a2 = 0.f, a3 = 0.f, ak = 0.f;
    for (int s = s0; s < s1; s += 8) {
        float kval = 0.f, vval = 0.f;
        if (s + lt < s1) {
            int tok = tl[s + lt];
            long bse = ((long)b * 4800 + tok) * 512 + h * 32 + ld;
            kval = b2f(kvab[bse]);
            vval = b2f(kvab[bse + 256]);
        }
        __syncthreads();
        kb[lt][ld] = kval;
        vb[lt][ld] = vval;
        __syncthreads();
#pragma unroll
        for (int j = 0; j < 8; j++) {
            float kd = kb[j][od];
            float4 vv = *(const float4*)&vb[j][oe];
            a0 += kd * vv.x; a1 += kd * vv.y; a2 += kd * vv.z; a3 += kd * vv.w;
            ak += kd;
        }
    }
    float* dst = kv + (((long)(b * NPROTO + c) * 8 + h) << 10) + od * 32 + oe;
    atomicAdd(dst + 0, a0);
    atomicAdd(dst + 1, a1);
    atomicAdd(dst + 2, a2);
    atomicAdd(dst + 3, a3);
    if ((t & 7) == 0)
        atomicAdd(ksum + (((long)(b * NPROTO + c) * 8 + h) << 5) + od, ak);
}

// ---------------- kv fp32 [d][e] + ksum → bf16 B-layout [e'][d], e'<48 -------
__global__ __launch_bounds__(256) void lft_kvconv_kernel(
    const float* __restrict__ kvb, const float* __restrict__ ksb,
    ushort* __restrict__ kvt)
{
    int bc = blockIdx.x;          // b*8+c
    int t = threadIdx.x;
    int h = t >> 5, d = t & 31;
    const float* kvsrc = kvb + ((long)bc * 8 + h) * 1024;
    const float* kssrc = ksb + ((long)bc * 8 + h) * 32;
    ushort* dst = kvt + ((long)bc * 8 + h) * 1536;
#pragma unroll
    for (int e = 0; e < 32; e++) dst[e * 32 + d] = f2b(kvsrc[d * 32 + e]);
    dst[32 * 32 + d] = f2b(kssrc[d]);
#pragma unroll
    for (int e = 33; e < 48; e++) dst[e * 32 + d] = 0;
}

// ---------------- msg via MFMA over X-SIDE class-sorted lists ----------------
__global__ __launch_bounds__(256) void lft_msg_kernel(
    const ushort* __restrict__ pq, const ushort* __restrict__ kvt,
    const int* __restrict__ tlist, const int* __restrict__ meta,
    ushort* __restrict__ msg)
{
    int chunk = blockIdx.x, c = blockIdx.y, b = blockIdx.z;
    int off = meta[(b * 8 + c) * 2], n = meta[(b * 8 + c) * 2 + 1];
    int per = (n + MSG_NCH - 1) / MSG_NCH;
    int s0 = chunk * per, s1 = min(s0 + per, n);
    if (s0 >= s1) return;
    const int* tl = tlist + b * 4800 + off;
    int t = threadIdx.x;
    int wave = t >> 6, lane = t & 63;
    int l16 = lane & 15, quad = lane >> 4;
    int bc = b * 8 + c;
    short8 bfr[2][3];
#pragma unroll
    for (int hh = 0; hh < 2; hh++) {
        int h = wave * 2 + hh;
        const ushort* kb = kvt + ((long)bc * 8 + h) * 1536;
#pragma unroll
        for (int nt = 0; nt < 3; nt++)
            bfr[hh][nt] = *(const short8*)&kb[(nt * 16 + l16) * 32 + quad * 8];
    }
    for (int s = s0; s < s1; s += 16) {
        int ia = min(s + l16, s1 - 1);
        int tokA = tl[ia];
        long rowA = (long)b * 4800 + tokA;
#pragma unroll
        for (int hh = 0; hh < 2; hh++) {
            int h = wave * 2 + hh;
            short8 a = *(const short8*)&pq[rowA * 256 + h * 32 + quad * 8];
            floatx4 n0 = {}, n1 = {}, dd = {};
            n0 = __builtin_amdgcn_mfma_f32_16x16x32_bf16(a, bfr[hh][0], n0, 0, 0, 0);
            n1 = __builtin_amdgcn_mfma_f32_16x16x32_bf16(a, bfr[hh][1], n1, 0, 0, 0);
            dd = __builtin_amdgcn_mfma_f32_16x16x32_bf16(a, bfr[hh][2], dd, 0, 0, 0);
#pragma unroll
            for (int r = 0; r < 4; r++) {
                int rowi = s + quad * 4 + r;
                float den = __shfl(dd[r], lane & 48, 64);
                float inv = 1.f / (den + 1e-6f);
                int tokr = __shfl(tokA, quad * 4 + r, 64);
                if (rowi < s1) {
                    long base = ((long)b * 4800 + tokr) * 256 + h * 32;
                    msg[base + l16]      = f2b(n0[r] * inv);
                    msg[base + 16 + l16] = f2b(n1[r] * inv);
                }
            }
        }
    }
}

extern "C" void kernel_launch(void* const* d_in, const int* in_sizes, int n_in,
                              void* d_out, int out_size, void* d_ws, size_t ws_size,
                              hipStream_t stream)
{
    (void)in_sizes; (void)n_in; (void)out_size; (void)ws_size;
    const float* feat0 = (const float*)d_in[0];
    const float* feat1 = (const float*)d_in[1];
    const int*   mask0 = (const int*)d_in[2];
    const int*   mask1 = (const int*)d_in[3];
    const float* f0wo  = (const float*)d_in[4];
    const float* f1wo  = (const float*)d_in[5];
    const float* proto = (const float*)d_in[6];
    const float* Wq = (const float*)d_in[7];
    const float* Wk = (const float*)d_in[8];
    const float* Wv = (const float*)d_in[9];
    const float* Wm = (const float*)d_in[10];
    const float* W1 = (const float*)d_in[11];
    const float* W2 = (const float*)d_in[12];
    const float* g1 = (const float*)d_in[13];
    const float* b1 = (const float*)d_in[14];
    const float* g2 = (const float*)d_in[15];
    const float* b2 = (const float*)d_in[16];
    float* out = (float*)d_out;
    float* ws = (float*)d_ws;

    // ---- workspace layout ----
    const long FSZ = 9830400L;           // 8*4800*256
    float* fa   = ws;                    // fp32 master feat0
    float* fb   = ws + FSZ;              // fp32 master feat1
    float* vbuf = ws + 3 * FSZ;          // bf16 [38400][512]: kv fused out, later hid
    ushort* ub  = (ushort*)(ws + 4 * FSZ);
    ushort* fa_bf  = ub;                 // bf16 shadow of fa
    ushort* fb_bf  = ub + FSZ;           // bf16 shadow of fb
    ushort* msg_bf = ub + 2 * FSZ;       // msg bf16; later LN1 bf16 out (in-place)
    ushort* qb_bf  = ub + 3 * FSZ;       // phi_q bf16
    ushort* wb     = ub + 4 * FSZ;       // bf16 transposed weights
    ushort* wb1    = wb + 16 * 65536;    // W1^T per layer [512][512]
    ushort* wb2    = wb1 + 4 * 262144;   // W2^T per layer [256][512]
    ushort* kvt    = wb2 + 4 * 131072;   // [64][8][48][32] bf16
    float* kvb = (float*)(kvt + 786432); // [B,NP,H,D,D] = 524288 f
    float* ksb = kvb + 524288;           // [B,NP,H,D]   = 16384 f
    int* cls0 = (int*)(ksb + 16384);
    int* cls1 = cls0 + 38400;
    int* tl0  = cls1 + 38400;            // class-sorted token lists
    int* tl1  = tl0 + 38400;
    int* meta = tl1 + 38400;             // [2][8][8][2] (off,cnt)
    ushort* kvab   = (ushort*)vbuf;      // [38400,512] bf16: [phi_k | v]
    ushort* hid_bf = (ushort*)vbuf;      // [38400,512] bf16 (after kv consumed)

    // one-time per launch
    lft_wconv_kernel<<<dim3(8, 8, 16), 256, 0, stream>>>(Wq, Wk, Wv, Wm, 256, 256, 4, wb);
    lft_wconv_kernel<<<dim3(16, 16, 4), 256, 0, stream>>>(W1, W1, W1, W1, 512, 512, 1, wb1);
    lft_wconv_kernel<<<dim3(16, 8, 4), 256, 0, stream>>>(W2, W2, W2, W2, 512, 256, 1, wb2);
    lft_cast_kernel<<<19200, 256, 0, stream>>>(feat0, feat1, fa_bf, fb_bf);
    hipMemcpyAsync(out + 20352000L, proto, 2048 * 4, hipMemcpyDeviceToDevice, stream);
    lft_class_kernel<<<19200, 256, 0, stream>>>(f0wo, f1wo, mask0, mask1, proto,
                                                out, cls0, cls1);
    lft_sort_kernel<<<16, 256, 0, stream>>>(cls0, cls1, tl0, tl1, meta);

    for (int li = 0; li < 4; li++) {
        const ushort* wq = wb + (size_t)(li * 4 + 0) * 65536;  // wq|wk|wv contig: [768][256]
        const ushort* wk = wb + (size_t)(li * 4 + 1) * 65536;  // wk|wv contiguous: [512][256]
        const ushort* wm = wb + (size_t)(li * 4 + 3) * 65536;
        const ushort* w1 = wb1 + (size_t)li * 262144;
        const ushort* w2 = wb2 + (size_t)li * 131072;
        const float* g1p = g1 + li * 256; const float* b1p = b1 + li * 256;
        const float* g2p = g2 + li * 256; const float* b2p = b2 + li * 256;

        auto call = [&](ushort* x_bf, ushort* s_bf, const int* clsx,
                        const int* tlx, const int* mtx,
                        const int* tls, const int* mts,
                        const float* residp, float* outFp) {
            dim3 blk(256);
            dim3 gA(2, 300), gB(4, 300), gQ(6, 300);
            if (x_bf == s_bf) {
                // self-self: fused [q|phi_k|v] = x@[Wq|Wk|Wv], N=768, split out:
                // cols<256 -> qb_bf (N=256), cols>=256 -> kvab (N=512)
                lft_mfma_gemm<<<gQ, blk, 0, stream>>>(x_bf, x_bf, 256, wq,
                    nullptr, qb_bf, 256, 256, 1, 512, kvab, 512, 256);
            } else {
                lft_mfma_gemm<<<gA, blk, 0, stream>>>(x_bf, x_bf, 256, wq,
                    nullptr, qb_bf, 256, 256, 1, 256, nullptr, 0, 0);
                lft_mfma_gemm<<<gB, blk, 0, stream>>>(s_bf, s_bf, 256, wk,
                    nullptr, kvab, 512, 256, 1, 256, nullptr, 0, 0);
            }
            hipMemsetAsync(kvb, 0, (524288 + 16384) * 4, stream);
            lft_kv_kernel<<<dim3(KV_NCH, 8, 64), blk, 0, stream>>>(kvab, tls, mts, kvb, ksb);
            lft_kvconv_kernel<<<64, blk, 0, stream>>>(kvb, ksb, kvt);
            lft_msg_kernel<<<dim3(MSG_NCH, 8, 8), blk, 0, stream>>>(qb_bf, kvt, tlx, mtx, msg_bf);
            // msg = LN(msg @ Wm)*g1+b1 -- fused GEMM+LN (8-wave), bf16 in-place
            lft_gemm_ln<<<300, dim3(512), 0, stream>>>(msg_bf, wm, 256, g1p, b1p,
                                                       nullptr, nullptr, nullptr, msg_bf);
            // hid = relu([x|msg]@W1) bf16
            lft_mfma_gemm<<<gB, blk, 0, stream>>>(x_bf, msg_bf, 256, w1,
                nullptr, hid_bf, 512, 512, 2, 512, nullptr, 0, 0);
            // out = valid ? resid + LN(hid@W2) : resid -- fused GEMM+LN+resid (8-wave)
            lft_gemm_ln<<<300, dim3(512), 0, stream>>>(hid_bf, w2, 512, g2p, b2p,
                                                       residp, clsx, outFp, x_bf);
        };

        const float* ra = (li == 0) ? feat0 : fa;
        const float* rb = (li == 0) ? feat1 : fb;
        float* oa = (li == 3) ? out : fa;
        float* ob = (li == 3) ? (out + FSZ) : fb;

        if ((li & 1) == 0) {           // self-self
            call(fa_bf, fa_bf, cls0, tl0, meta,       tl0, meta,       ra, oa);
            call(fb_bf, fb_bf, cls1, tl1, meta + 128, tl1, meta + 128, rb, ob);
        } else {                       // cross-self: x=feat0 iterates tl0, gathers tl1
            call(fa_bf, fb_bf, cls0, tl0, meta,       tl1, meta + 128, ra, oa);
            call(fb_bf, fa_bf, cls1, tl1, meta + 128, tl0, meta,      rb, ob);
        }
    }
}

// Round 12
// 1578.857 us; speedup vs baseline: 1.1224x; 1.0425x over previous
//
#include <hip/hip_runtime.h>
#include <math.h>

#define NPROTO 8
#define KV_NCH 4
#define MSG_NCH 8

typedef __attribute__((ext_vector_type(8))) short short8;
typedef __attribute__((ext_vector_type(4))) float floatx4;

static __device__ __forceinline__ ushort f2b(float f) {
    unsigned u = __builtin_bit_cast(unsigned, f);
    unsigned r = (u + 0x7fffu + ((u >> 16) & 1u)) >> 16;
    return (ushort)r;
}

static __device__ __forceinline__ float b2f(ushort u) {
    return __builtin_bit_cast(float, ((unsigned)u) << 16);
}

typedef __attribute__((address_space(1))) void gvoid;
typedef __attribute__((address_space(3))) void lvoid;

// async global->LDS, 16B per lane. LDS dest must be lane-contiguous per wave.
static __device__ __forceinline__ void gload_lds16(const ushort* g, ushort* l) {
    __builtin_amdgcn_global_load_lds((gvoid*)(void*)g, (lvoid*)l, 16, 0, 0);
}

// ---------------- prototype projection / argmax-class kernel ----------------
__global__ __launch_bounds__(256) void lft_class_kernel(
    const float* __restrict__ f0wo, const float* __restrict__ f1wo,
    const int* __restrict__ mask0, const int* __restrict__ mask1,
    const float* __restrict__ proto,
    float* out, int* cls0, int* cls1)
{
    __shared__ float pr[2048];
    int t = threadIdx.x;
    *(float4*)&pr[t * 4]        = *(const float4*)&proto[t * 4];
    *(float4*)&pr[1024 + t * 4] = *(const float4*)&proto[1024 + t * 4];
    __syncthreads();
    int wave = t >> 6, lane = t & 63;
    long token = (long)blockIdx.x * 4 + wave;
    const float* fsrc; const int* msrc; float* fpout; float* clsout; int* clsarr; long tok;
    if (token < 38400) {
        tok = token; fsrc = f0wo; msrc = mask0;
        fpout = out + 19737600L; clsout = out + 19660800L; clsarr = cls0;
    } else {
        tok = token - 38400; fsrc = f1wo; msrc = mask1;
        fpout = out + 20044800L; clsout = out + 19699200L; clsarr = cls1;
    }
    float4 f = *(const float4*)&fsrc[tok * 256 + lane * 4];
    float s[NPROTO];
#pragma unroll
    for (int p = 0; p < NPROTO; p++) {
        float4 pv = *(const float4*)&pr[p * 256 + lane * 4];
        s[p] = f.x * pv.x + f.y * pv.y + f.z * pv.z + f.w * pv.w;
    }
    float k0_ = (lane & 1) ? s[4] : s[0], d0 = (lane & 1) ? s[0] : s[4];
    float k1_ = (lane & 1) ? s[5] : s[1], d1 = (lane & 1) ? s[1] : s[5];
    float k2_ = (lane & 1) ? s[6] : s[2], d2 = (lane & 1) ? s[2] : s[6];
    float k3_ = (lane & 1) ? s[7] : s[3], d3 = (lane & 1) ? s[3] : s[7];
    float w0 = k0_ + __shfl_xor(d0, 1, 64);
    float w1 = k1_ + __shfl_xor(d1, 1, 64);
    float w2 = k2_ + __shfl_xor(d2, 1, 64);
    float w3 = k3_ + __shfl_xor(d3, 1, 64);
    float u0k = (lane & 2) ? w2 : w0, u0d = (lane & 2) ? w0 : w2;
    float u1k = (lane & 2) ? w3 : w1, u1d = (lane & 2) ? w1 : w3;
    float x0 = u0k + __shfl_xor(u0d, 2, 64);
    float x1 = u1k + __shfl_xor(u1d, 2, 64);
    float yk = (lane & 4) ? x1 : x0, yd = (lane & 4) ? x0 : x1;
    float sc = yk + __shfl_xor(yd, 4, 64);
    sc += __shfl_xor(sc, 8, 64);
    sc += __shfl_xor(sc, 16, 64);
    sc += __shfl_xor(sc, 32, 64);
    int p = ((lane & 1) << 2) | (lane & 2) | ((lane >> 2) & 1);
    if (lane < 8) fpout[tok * 8 + p] = sc;
    float bv = sc; int bi = p;
#pragma unroll
    for (int o = 1; o < 8; o <<= 1) {
        float ov = __shfl_xor(bv, o, 64);
        int oi = __shfl_xor(bi, o, 64);
        if (ov > bv || (ov == bv && oi < bi)) { bv = ov; bi = oi; }
    }
    if (lane == 0) {
        clsout[tok] = (float)bi;
        clsarr[tok] = msrc[tok] ? bi : -1;
    }
}

// ---------------- counting sort of tokens by (batch,class) -------------------
__global__ __launch_bounds__(256) void lft_sort_kernel(
    const int* __restrict__ cls0, const int* __restrict__ cls1,
    int* tl0, int* tl1, int* meta)
{
    int g = blockIdx.x; int L = g >> 3, b = g & 7;
    const int* cls = (L ? cls1 : cls0) + b * 4800;
    int* tl = (L ? tl1 : tl0) + b * 4800;
    int* mt = meta + (L * 8 + b) * 16;
    __shared__ int cnt[8], base[8], pos[8];
    int t = threadIdx.x;
    if (t < 8) cnt[t] = 0;
    __syncthreads();
    for (int tok = t; tok < 4800; tok += 256) {
        int c = cls[tok];
        if (c >= 0) atomicAdd(&cnt[c], 1);
    }
    __syncthreads();
    if (t == 0) {
        int s = 0;
        for (int c = 0; c < 8; c++) { base[c] = s; pos[c] = s; s += cnt[c]; }
    }
    __syncthreads();
    if (t < 8) { mt[t * 2] = base[t]; mt[t * 2 + 1] = cnt[t]; }
    for (int tok = t; tok < 4800; tok += 256) {
        int c = cls[tok];
        if (c >= 0) { int p = atomicAdd(&pos[c], 1); tl[p] = tok; }
    }
}

// ---------------- weight convert + transpose: Wt[n*K+k] = bf16(W[k*N+n]) ----
__global__ __launch_bounds__(256) void lft_wconv_kernel(
    const float* W0, const float* W1p, const float* W2p, const float* W3p,
    int K, int N, int nTypes, ushort* dst)
{
    int z = blockIdx.z;
    int li = z / nTypes, mi = z % nTypes;
    const float* srcs[4] = {W0, W1p, W2p, W3p};
    const float* src = srcs[mi] + (size_t)li * K * N;
    ushort* outp = dst + (size_t)z * K * N;
    __shared__ float tile[32][33];
    int k0 = blockIdx.x * 32, n0 = blockIdx.y * 32;
    int t = threadIdx.x;
    int r = t >> 3, c4 = (t & 7) << 2;
    float4 v = *(const float4*)&src[(size_t)(k0 + r) * N + n0 + c4];
    tile[r][c4] = v.x; tile[r][c4 + 1] = v.y; tile[r][c4 + 2] = v.z; tile[r][c4 + 3] = v.w;
    __syncthreads();
    ushort4 o;
    o.x = f2b(tile[c4 + 0][r]);
    o.y = f2b(tile[c4 + 1][r]);
    o.z = f2b(tile[c4 + 2][r]);
    o.w = f2b(tile[c4 + 3][r]);
    *(ushort4*)&outp[(size_t)(n0 + r) * K + k0 + c4] = o;
}

// ---------------- bf16 cast of feat0/feat1 (shadows only) ----------------
__global__ __launch_bounds__(256) void lft_cast_kernel(
    const float* __restrict__ f0, const float* __restrict__ f1,
    ushort* fab, ushort* fbb)
{
    long idx = ((long)blockIdx.x * 256 + threadIdx.x) * 4;
    const float* src; ushort* db; long o;
    if (idx < 9830400L) { src = f0; db = fab; o = idx; }
    else                { src = f1; db = fbb; o = idx - 9830400L; }
    float4 v = *(const float4*)&src[o];
    ushort4 u; u.x = f2b(v.x); u.y = f2b(v.y); u.z = f2b(v.z); u.w = f2b(v.w);
    *(ushort4*)&db[o] = u;
}

// ---------------- bf16 MFMA GEMM, 2-phase pipelined: C = act([A0|A1] @ Wt^T) -
// 128x128 tile, BK=32, double-buffered LDS, global_load_lds dwordx4,
// counted vmcnt(4) + raw s_barrier. LDS bank-swizzle on source col (rule #21).
// XCD-chunked remap (T1). TRANSPOSED-OPERAND epilogue: mfma(B,A) gives each
// lane 4 CONSECUTIVE cols of one row -> ushort4/float4 stores.
// Optional split output (Cb2/N2/colSplit): block-uniform dest select by n0.
__global__ __launch_bounds__(256) void lft_mfma_gemm(
    const ushort* __restrict__ A0, const ushort* __restrict__ A1, int kSplit,
    const ushort* __restrict__ Wt,
    float* Cf, ushort* Cb, int N, int K, int act, int actSplit,
    ushort* Cb2, int N2, int colSplit)
{
    __shared__ ushort As[2][128 * 32];
    __shared__ ushort Bs[2][128 * 32];
    int t = threadIdx.x;
    int nbx = gridDim.x;
    int nwg = nbx * gridDim.y;
    int orig = blockIdx.y * nbx + blockIdx.x;
    int q8 = nwg >> 3;
    int swz = (nwg & 7) ? orig : ((orig & 7) * q8 + (orig >> 3));
    int bx = swz % nbx, by = swz / nbx;
    int m0 = by << 7;
    int n0 = bx << 7;
    int wave = t >> 6, lane = t & 63;
    int wm = wave >> 1, wn = wave & 1;
    int l16 = lane & 15, quad = lane >> 4;
    int r = t >> 2;            // 0..63: row within half-tile
    int cu = (t & 3) << 3;     // linear LDS dest col offset (ushorts)
    int fso = (((t & 3) ^ ((r ^ (r >> 2)) & 3)) << 3);  // swizzled SOURCE col
    floatx4 acc[4][4] = {};

    auto stage = [&](int buf, int k0) {
        const ushort* Asrc; int kcol, ldA;
        if (k0 < kSplit) { Asrc = A0; kcol = k0;          ldA = kSplit; }
        else             { Asrc = A1; kcol = k0 - kSplit; ldA = K - kSplit; }
        gload_lds16(&Asrc[(size_t)(m0 + r) * ldA + kcol + fso],      &As[buf][r * 32 + cu]);
        gload_lds16(&Asrc[(size_t)(m0 + r + 64) * ldA + kcol + fso], &As[buf][(r + 64) * 32 + cu]);
        gload_lds16(&Wt[(size_t)(n0 + r) * K + k0 + fso],            &Bs[buf][r * 32 + cu]);
        gload_lds16(&Wt[(size_t)(n0 + r + 64) * K + k0 + fso],       &Bs[buf][(r + 64) * 32 + cu]);
    };

    int qs = ((quad ^ ((l16 ^ (l16 >> 2)) & 3)) << 3);  // swizzled READ col
    stage(0, 0);
    int cur = 0;
    for (int k0 = 0; k0 < K; k0 += 32) {
        if (k0 + 32 < K) {
            stage(cur ^ 1, k0 + 32);
            asm volatile("s_waitcnt vmcnt(4)" ::: "memory");
        } else {
            asm volatile("s_waitcnt vmcnt(0)" ::: "memory");
        }
        __builtin_amdgcn_s_barrier();
        short8 af[4], bfr[4];
#pragma unroll
        for (int i = 0; i < 4; i++) {
            af[i]  = *(const short8*)&As[cur][(wm * 64 + i * 16 + l16) * 32 + qs];
            bfr[i] = *(const short8*)&Bs[cur][(wn * 64 + i * 16 + l16) * 32 + qs];
        }
#pragma unroll
        for (int i = 0; i < 4; i++)
#pragma unroll
            for (int j = 0; j < 4; j++)
                acc[i][j] = __builtin_amdgcn_mfma_f32_16x16x32_bf16(bfr[j], af[i], acc[i][j], 0, 0, 0);
        asm volatile("" ::: "memory");
        __builtin_amdgcn_s_barrier();
        cur ^= 1;
    }
    int effAct = (n0 >= actSplit) ? 0 : act;
    float* Cfp = Cf;
    ushort* Cbp = Cb;
    int ldC = N, cb0 = n0;
    if (Cb2 && n0 >= colSplit) { Cbp = Cb2; Cfp = nullptr; ldC = N2; cb0 = n0 - colSplit; }
#pragma unroll
    for (int i = 0; i < 4; i++) {
        long rowb = m0 + wm * 64 + i * 16 + l16;
#pragma unroll
        for (int j = 0; j < 4; j++) {
            int colb = cb0 + wn * 64 + j * 16 + quad * 4;
            float v0 = acc[i][j][0], v1 = acc[i][j][1], v2 = acc[i][j][2], v3 = acc[i][j][3];
            if (effAct == 1) {
                v0 = v0 > 0.f ? v0 + 1.f : __expf(v0);
                v1 = v1 > 0.f ? v1 + 1.f : __expf(v1);
                v2 = v2 > 0.f ? v2 + 1.f : __expf(v2);
                v3 = v3 > 0.f ? v3 + 1.f : __expf(v3);
            } else if (effAct == 2) {
                v0 = fmaxf(v0, 0.f); v1 = fmaxf(v1, 0.f);
                v2 = fmaxf(v2, 0.f); v3 = fmaxf(v3, 0.f);
            }
            if (Cfp) {
                float4 f4; f4.x = v0; f4.y = v1; f4.z = v2; f4.w = v3;
                *(float4*)&Cfp[rowb * ldC + colb] = f4;
            }
            if (Cbp) {
                ushort4 u4;
                u4.x = f2b(v0); u4.y = f2b(v1); u4.z = f2b(v2); u4.w = f2b(v3);
                *(ushort4*)&Cbp[rowb * ldC + colb] = u4;
            }
        }
    }
}

// ---------------- fused GEMM (N=256 full-row) + LayerNorm epilogue -----------
// 64x256 tile, BK=32, 256 threads / 4 waves (1 x 4 col-quarters): each wave =
// 64x64 sub-tile (16 MFMA + 8 ds_read / K-step, proven shape). 600 blocks ->
// 2-3 resident/CU hides barrier stalls. 5 gload_lds16/thread, vmcnt(5).
// Block owns FULL rows -> LN epilogue: quad-shfl + red[4][64] combine.
__global__ __launch_bounds__(256) void lft_gemm_ln(
    const ushort* __restrict__ A, const ushort* __restrict__ Wt, int K,
    const float* __restrict__ g, const float* __restrict__ bb,
    const float* __restrict__ resid, const int* __restrict__ cls,
    float* outF, ushort* __restrict__ outB)
{
    __shared__ ushort As[2][64 * 32];
    __shared__ ushort Bs[2][256 * 32];
    __shared__ float red[4][64][2];
    int t = threadIdx.x;                  // 0..255
    long m0 = (long)blockIdx.x << 6;
    int wave = t >> 6, lane = t & 63;
    int wn = wave;                        // 1 x 4 wave grid (col quarters)
    int l16 = lane & 15, quad = lane >> 4;
    int r = t >> 2;                       // 0..63
    int cu = (t & 3) << 3;
    int fso = (((t & 3) ^ ((r ^ (r >> 2)) & 3)) << 3);
    // B slab rows s*64+r: f(s*64+r)==f(r) since 64 contributes 0 to both XOR terms
    floatx4 acc[4][4] = {};

    auto stage = [&](int buf, int k0) {
        gload_lds16(&A[(m0 + r) * K + k0 + fso], &As[buf][r * 32 + cu]);
#pragma unroll
        for (int s = 0; s < 4; s++)
            gload_lds16(&Wt[(size_t)(s * 64 + r) * K + k0 + fso],
                        &Bs[buf][(s * 64 + r) * 32 + cu]);
    };

    int qs = ((quad ^ ((l16 ^ (l16 >> 2)) & 3)) << 3);
    stage(0, 0);
    int cur = 0;
    for (int k0 = 0; k0 < K; k0 += 32) {
        if (k0 + 32 < K) {
            stage(cur ^ 1, k0 + 32);
            asm volatile("s_waitcnt vmcnt(5)" ::: "memory");
        } else {
            asm volatile("s_waitcnt vmcnt(0)" ::: "memory");
        }
        __builtin_amdgcn_s_barrier();
        short8 af[4], bfr[4];
#pragma unroll
        for (int i = 0; i < 4; i++) {
            af[i]  = *(const short8*)&As[cur][(i * 16 + l16) * 32 + qs];
            bfr[i] = *(const short8*)&Bs[cur][(wn * 64 + i * 16 + l16) * 32 + qs];
        }
        // transposed-operand: lane l16 = row (m-local), quad*4+rr = 4 consec cols
#pragma unroll
        for (int i = 0; i < 4; i++)
#pragma unroll
            for (int j = 0; j < 4; j++)
                acc[i][j] = __builtin_amdgcn_mfma_f32_16x16x32_bf16(bfr[j], af[i], acc[i][j], 0, 0, 0);
        asm volatile("" ::: "memory");
        __builtin_amdgcn_s_barrier();
        cur ^= 1;
    }
    // ---- row sums: lane covers 16 cols of each of its 4 row-frags; reduce
    // over quad (shfl), then combine the 4 col-quarter waves via LDS ----
#pragma unroll
    for (int i = 0; i < 4; i++) {
        float s = 0.f, sq = 0.f;
#pragma unroll
        for (int j = 0; j < 4; j++)
#pragma unroll
            for (int rr = 0; rr < 4; rr++) { float v = acc[i][j][rr]; s += v; sq += v * v; }
        s  += __shfl_xor(s, 16, 64);  sq += __shfl_xor(sq, 16, 64);
        s  += __shfl_xor(s, 32, 64);  sq += __shfl_xor(sq, 32, 64);
        if (quad == 0) {
            int rl = i * 16 + l16;
            red[wn][rl][0] = s;
            red[wn][rl][1] = sq;
        }
    }
    __syncthreads();
#pragma unroll
    for (int i = 0; i < 4; i++) {
        int rl = i * 16 + l16;
        long row = m0 + rl;
        float tsum = red[0][rl][0] + red[1][rl][0] + red[2][rl][0] + red[3][rl][0];
        float tsq  = red[0][rl][1] + red[1][rl][1] + red[2][rl][1] + red[3][rl][1];
        float mean = tsum * (1.0f / 256.0f);
        float var  = tsq * (1.0f / 256.0f) - mean * mean;
        float rsq  = rsqrtf(var + 1e-5f);
        bool keep = true;
        if (cls) keep = (cls[row] >= 0);
#pragma unroll
        for (int j = 0; j < 4; j++) {
            int col = wn * 64 + j * 16 + quad * 4;
            float4 gv = *(const float4*)&g[col];
            float4 bv = *(const float4*)&bb[col];
            float y0 = (acc[i][j][0] - mean) * rsq * gv.x + bv.x;
            float y1 = (acc[i][j][1] - mean) * rsq * gv.y + bv.y;
            float y2 = (acc[i][j][2] - mean) * rsq * gv.z + bv.z;
            float y3 = (acc[i][j][3] - mean) * rsq * gv.w + bv.w;
            if (resid) {
                float4 xr = *(const float4*)&resid[row * 256 + col];
                if (keep) { y0 += xr.x; y1 += xr.y; y2 += xr.z; y3 += xr.w; }
                else      { y0 = xr.x;  y1 = xr.y;  y2 = xr.z;  y3 = xr.w; }
            }
            if (outF) {
                float4 f4; f4.x = y0; f4.y = y1; f4.z = y2; f4.w = y3;
                *(float4*)&outF[row * 256 + col] = f4;
            }
            ushort4 u4;
            u4.x = f2b(y0); u4.y = f2b(y1); u4.z = f2b(y2); u4.w = f2b(y3);
            *(ushort4*)&outB[row * 256 + col] = u4;
        }
    }
}

// ---------------- per-class KV / Ksum reduction (SRC-side token lists) --------
// kvab: fused bf16 [38400][512], cols 0..255 = phi_k, 256..511 = v
__global__ __launch_bounds__(256) void lft_kv_kernel(
    const ushort* __restrict__ kvab,
    const int* __restrict__ tlist, const int* __restrict__ meta,
    float* kv, float* ksum)
{
    int chunk = blockIdx.x, c = blockIdx.y;
    int b = blockIdx.z >> 3, h = blockIdx.z & 7;
    int off = meta[(b * 8 + c) * 2], n = meta[(b * 8 + c) * 2 + 1];
    int per = (n + KV_NCH - 1) / KV_NCH;
    int s0 = chunk * per;
    int s1 = min(s0 + per, n);
    if (s0 >= s1) return;
    const int* tl = tlist + b * 4800 + off;
    int t = threadIdx.x;
    __shared__ float kb[8][32];
    __shared__ float vb[8][32];
    int od = t >> 3, oe = (t & 7) << 2;
    int lt = t >> 5, ld = t & 31;
    float a0 = 0.f, a1 = 0.f, a2 = 0.f, a3 = 0.f, ak = 0.f;
    for (int s = s0; s < s1; s += 8) {
        float kval = 0.f, vval = 0.f;
        if (s + lt < s1) {
            int tok = tl[s + lt];
            long bse = ((long)b * 4800 + tok) * 512 + h * 32 + ld;
            kval = b2f(kvab[bse]);
            vval = b2f(kvab[bse + 256]);
        }
        __syncthreads();
        kb[lt][ld] = kval;
        vb[lt][ld] = vval;
        __syncthreads();
#pragma unroll
        for (int j = 0; j < 8; j++) {
            float kd = kb[j][od];
            float4 vv = *(const float4*)&vb[j][oe];
            a0 += kd * vv.x; a1 += kd * vv.y; a2 += kd * vv.z; a3 += kd * vv.w;
            ak += kd;
        }
    }
    float* dst = kv + (((long)(b * NPROTO + c) * 8 + h) << 10) + od * 32 + oe;
    atomicAdd(dst + 0, a0);
    atomicAdd(dst + 1, a1);
    atomicAdd(dst + 2, a2);
    atomicAdd(dst + 3, a3);
    if ((t & 7) == 0)
        atomicAdd(ksum + (((long)(b * NPROTO + c) * 8 + h) << 5) + od, ak);
}

// ---------------- kv fp32 [d][e] + ksum → bf16 B-layout [e'][d], e'<48 -------
__global__ __launch_bounds__(256) void lft_kvconv_kernel(
    const float* __restrict__ kvb, const float* __restrict__ ksb,
    ushort* __restrict__ kvt)
{
    int bc = blockIdx.x;          // b*8+c
    int t = threadIdx.x;
    int h = t >> 5, d = t & 31;
    const float* kvsrc = kvb + ((long)bc * 8 + h) * 1024;
    const float* kssrc = ksb + ((long)bc * 8 + h) * 32;
    ushort* dst = kvt + ((long)bc * 8 + h) * 1536;
#pragma unroll
    for (int e = 0; e < 32; e++) dst[e * 32 + d] = f2b(kvsrc[d * 32 + e]);
    dst[32 * 32 + d] = f2b(kssrc[d]);
#pragma unroll
    for (int e = 33; e < 48; e++) dst[e * 32 + d] = 0;
}

// ---------------- msg via MFMA over X-SIDE class-sorted lists ----------------
__global__ __launch_bounds__(256) void lft_msg_kernel(
    const ushort* __restrict__ pq, const ushort* __restrict__ kvt,
    const int* __restrict__ tlist, const int* __restrict__ meta,
    ushort* __restrict__ msg)
{
    int chunk = blockIdx.x, c = blockIdx.y, b = blockIdx.z;
    int off = meta[(b * 8 + c) * 2], n = meta[(b * 8 + c) * 2 + 1];
    int per = (n + MSG_NCH - 1) / MSG_NCH;
    int s0 = chunk * per, s1 = min(s0 + per, n);
    if (s0 >= s1) return;
    const int* tl = tlist + b * 4800 + off;
    int t = threadIdx.x;
    int wave = t >> 6, lane = t & 63;
    int l16 = lane & 15, quad = lane >> 4;
    int bc = b * 8 + c;
    short8 bfr[2][3];
#pragma unroll
    for (int hh = 0; hh < 2; hh++) {
        int h = wave * 2 + hh;
        const ushort* kb = kvt + ((long)bc * 8 + h) * 1536;
#pragma unroll
        for (int nt = 0; nt < 3; nt++)
            bfr[hh][nt] = *(const short8*)&kb[(nt * 16 + l16) * 32 + quad * 8];
    }
    for (int s = s0; s < s1; s += 16) {
        int ia = min(s + l16, s1 - 1);
        int tokA = tl[ia];
        long rowA = (long)b * 4800 + tokA;
#pragma unroll
        for (int hh = 0; hh < 2; hh++) {
            int h = wave * 2 + hh;
            short8 a = *(const short8*)&pq[rowA * 256 + h * 32 + quad * 8];
            floatx4 n0 = {}, n1 = {}, dd = {};
            n0 = __builtin_amdgcn_mfma_f32_16x16x32_bf16(a, bfr[hh][0], n0, 0, 0, 0);
            n1 = __builtin_amdgcn_mfma_f32_16x16x32_bf16(a, bfr[hh][1], n1, 0, 0, 0);
            dd = __builtin_amdgcn_mfma_f32_16x16x32_bf16(a, bfr[hh][2], dd, 0, 0, 0);
#pragma unroll
            for (int r = 0; r < 4; r++) {
                int rowi = s + quad * 4 + r;
                float den = __shfl(dd[r], lane & 48, 64);
                float inv = 1.f / (den + 1e-6f);
                int tokr = __shfl(tokA, quad * 4 + r, 64);
                if (rowi < s1) {
                    long base = ((long)b * 4800 + tokr) * 256 + h * 32;
                    msg[base + l16]      = f2b(n0[r] * inv);
                    msg[base + 16 + l16] = f2b(n1[r] * inv);
                }
            }
        }
    }
}

extern "C" void kernel_launch(void* const* d_in, const int* in_sizes, int n_in,
                              void* d_out, int out_size, void* d_ws, size_t ws_size,
                              hipStream_t stream)
{
    (void)in_sizes; (void)n_in; (void)out_size; (void)ws_size;
    const float* feat0 = (const float*)d_in[0];
    const float* feat1 = (const float*)d_in[1];
    const int*   mask0 = (const int*)d_in[2];
    const int*   mask1 = (const int*)d_in[3];
    const float* f0wo  = (const float*)d_in[4];
    const float* f1wo  = (const float*)d_in[5];
    const float* proto = (const float*)d_in[6];
    const float* Wq = (const float*)d_in[7];
    const float* Wk = (const float*)d_in[8];
    const float* Wv = (const float*)d_in[9];
    const float* Wm = (const float*)d_in[10];
    const float* W1 = (const float*)d_in[11];
    const float* W2 = (const float*)d_in[12];
    const float* g1 = (const float*)d_in[13];
    const float* b1 = (const float*)d_in[14];
    const float* g2 = (const float*)d_in[15];
    const float* b2 = (const float*)d_in[16];
    float* out = (float*)d_out;
    float* ws = (float*)d_ws;

    // ---- workspace layout ----
    const long FSZ = 9830400L;           // 8*4800*256
    float* fa   = ws;                    // fp32 master feat0
    float* fb   = ws + FSZ;              // fp32 master feat1
    float* vbuf = ws + 3 * FSZ;          // bf16 [38400][512]: kv fused out, later hid
    ushort* ub  = (ushort*)(ws + 4 * FSZ);
    ushort* fa_bf  = ub;                 // bf16 shadow of fa
    ushort* fb_bf  = ub + FSZ;           // bf16 shadow of fb
    ushort* msg_bf = ub + 2 * FSZ;       // msg bf16; later LN1 bf16 out (in-place)
    ushort* qb_bf  = ub + 3 * FSZ;       // phi_q bf16
    ushort* wb     = ub + 4 * FSZ;       // bf16 transposed weights
    ushort* wb1    = wb + 16 * 65536;    // W1^T per layer [512][512]
    ushort* wb2    = wb1 + 4 * 262144;   // W2^T per layer [256][512]
    ushort* kvt    = wb2 + 4 * 131072;   // [64][8][48][32] bf16
    float* kvb = (float*)(kvt + 786432); // [B,NP,H,D,D] = 524288 f
    float* ksb = kvb + 524288;           // [B,NP,H,D]   = 16384 f
    int* cls0 = (int*)(ksb + 16384);
    int* cls1 = cls0 + 38400;
    int* tl0  = cls1 + 38400;            // class-sorted token lists
    int* tl1  = tl0 + 38400;
    int* meta = tl1 + 38400;             // [2][8][8][2] (off,cnt)
    ushort* kvab   = (ushort*)vbuf;      // [38400,512] bf16: [phi_k | v]
    ushort* hid_bf = (ushort*)vbuf;      // [38400,512] bf16 (after kv consumed)

    // one-time per launch
    lft_wconv_kernel<<<dim3(8, 8, 16), 256, 0, stream>>>(Wq, Wk, Wv, Wm, 256, 256, 4, wb);
    lft_wconv_kernel<<<dim3(16, 16, 4), 256, 0, stream>>>(W1, W1, W1, W1, 512, 512, 1, wb1);
    lft_wconv_kernel<<<dim3(16, 8, 4), 256, 0, stream>>>(W2, W2, W2, W2, 512, 256, 1, wb2);
    lft_cast_kernel<<<19200, 256, 0, stream>>>(feat0, feat1, fa_bf, fb_bf);
    hipMemcpyAsync(out + 20352000L, proto, 2048 * 4, hipMemcpyDeviceToDevice, stream);
    lft_class_kernel<<<19200, 256, 0, stream>>>(f0wo, f1wo, mask0, mask1, proto,
                                                out, cls0, cls1);
    lft_sort_kernel<<<16, 256, 0, stream>>>(cls0, cls1, tl0, tl1, meta);

    for (int li = 0; li < 4; li++) {
        const ushort* wq = wb + (size_t)(li * 4 + 0) * 65536;  // wq|wk|wv contig: [768][256]
        const ushort* wk = wb + (size_t)(li * 4 + 1) * 65536;  // wk|wv contiguous: [512][256]
        const ushort* wm = wb + (size_t)(li * 4 + 3) * 65536;
        const ushort* w1 = wb1 + (size_t)li * 262144;
        const ushort* w2 = wb2 + (size_t)li * 131072;
        const float* g1p = g1 + li * 256; const float* b1p = b1 + li * 256;
        const float* g2p = g2 + li * 256; const float* b2p = b2 + li * 256;

        auto call = [&](ushort* x_bf, ushort* s_bf, const int* clsx,
                        const int* tlx, const int* mtx,
                        const int* tls, const int* mts,
                        const float* residp, float* outFp) {
            dim3 blk(256);
            dim3 gA(2, 300), gB(4, 300), gQ(6, 300);
            if (x_bf == s_bf) {
                // self-self: fused [q|phi_k|v] = x@[Wq|Wk|Wv], N=768, split out:
                // cols<256 -> qb_bf (N=256), cols>=256 -> kvab (N=512)
                lft_mfma_gemm<<<gQ, blk, 0, stream>>>(x_bf, x_bf, 256, wq,
                    nullptr, qb_bf, 256, 256, 1, 512, kvab, 512, 256);
            } else {
                lft_mfma_gemm<<<gA, blk, 0, stream>>>(x_bf, x_bf, 256, wq,
                    nullptr, qb_bf, 256, 256, 1, 256, nullptr, 0, 0);
                lft_mfma_gemm<<<gB, blk, 0, stream>>>(s_bf, s_bf, 256, wk,
                    nullptr, kvab, 512, 256, 1, 256, nullptr, 0, 0);
            }
            hipMemsetAsync(kvb, 0, (524288 + 16384) * 4, stream);
            lft_kv_kernel<<<dim3(KV_NCH, 8, 64), blk, 0, stream>>>(kvab, tls, mts, kvb, ksb);
            lft_kvconv_kernel<<<64, blk, 0, stream>>>(kvb, ksb, kvt);
            lft_msg_kernel<<<dim3(MSG_NCH, 8, 8), blk, 0, stream>>>(qb_bf, kvt, tlx, mtx, msg_bf);
            // msg = LN(msg @ Wm)*g1+b1 -- fused GEMM+LN (64-row tiles), bf16 in-place
            lft_gemm_ln<<<600, blk, 0, stream>>>(msg_bf, wm, 256, g1p, b1p,
                                                 nullptr, nullptr, nullptr, msg_bf);
            // hid = relu([x|msg]@W1) bf16
            lft_mfma_gemm<<<gB, blk, 0, stream>>>(x_bf, msg_bf, 256, w1,
                nullptr, hid_bf, 512, 512, 2, 512, nullptr, 0, 0);
            // out = valid ? resid + LN(hid@W2) : resid -- fused GEMM+LN+resid
            lft_gemm_ln<<<600, blk, 0, stream>>>(hid_bf, w2, 512, g2p, b2p,
                                                 residp, clsx, outFp, x_bf);
        };

        const float* ra = (li == 0) ? feat0 : fa;
        const float* rb = (li == 0) ? feat1 : fb;
        float* oa = (li == 3) ? out : fa;
        float* ob = (li == 3) ? (out + FSZ) : fb;

        if ((li & 1) == 0) {           // self-self
            call(fa_bf, fa_bf, cls0, tl0, meta,       tl0, meta,       ra, oa);
            call(fb_bf, fb_bf, cls1, tl1, meta + 128, tl1, meta + 128, rb, ob);
        } else {                       // cross-self: x=feat0 iterates tl0, gathers tl1
            call(fa_bf, fb_bf, cls0, tl0, meta,       tl1, meta + 128, ra, oa);
            call(fb_bf, fa_bf, cls1, tl1, meta + 128, tl0, meta,      rb, ob);
        }
    }
}